// Round 9
// baseline (4946.923 us; speedup 1.0000x reference)
//
#include <hip/hip_runtime.h>
#include <cstdint>
#include <cstddef>

#define NB 32       // batch
#define NT 512      // time steps
#define ND 512      // input dim D
#define NH 1024     // hidden H
#define NC4 4608    // 4H + 4*HH (fused GEMM N)

typedef short sh8 __attribute__((ext_vector_type(8)));   // 8 bf16 (raw bits)
typedef float f4  __attribute__((ext_vector_type(4)));
typedef unsigned int u4 __attribute__((ext_vector_type(4)));

__device__ __forceinline__ unsigned short f2bf(float x) {
  union { float f; unsigned u; } v; v.f = x;
  unsigned r = v.u + 0x7FFFu + ((v.u >> 16) & 1u);   // RNE
  return (unsigned short)(r >> 16);
}
__device__ __forceinline__ float bf2f(unsigned short b) {
  union { unsigned u; float f; } v; v.u = ((unsigned)b) << 16; return v.f;
}
__device__ __forceinline__ float blo(unsigned w) { union { unsigned u; float f; } v; v.u = w << 16; return v.f; }
__device__ __forceinline__ float bhi(unsigned w) { union { unsigned u; float f; } v; v.u = w & 0xFFFF0000u; return v.f; }
__device__ __forceinline__ float asf(unsigned u) { union { unsigned u; float f; } v; v.u = u; return v.f; }
__device__ __forceinline__ unsigned asu(float f) { union { float f; unsigned u; } v; v.f = f; return v.u; }

// MALL-coherent 16B load: bypasses L1/L2 (sc0 sc1).
#define LD16(dst, base, OFFSTR)                                         \
  asm volatile("global_load_dwordx4 %0, %1, off offset:" OFFSTR " sc0 sc1" \
               : "=v"(dst) : "v"(base))

// ---------------------------------------------------------------------------
// prep: hyper gate weights -> bf16 transposed; pz weights -> fp32 transposed;
//       zero hbuf (tag 0 == step 0); zero 96 flag lines
// ---------------------------------------------------------------------------
__global__ __launch_bounds__(256) void k_prep(
    const float* __restrict__ wih, const float* __restrict__ wgh,
    const float* __restrict__ wfh, const float* __restrict__ woh,
    const float* __restrict__ pzx, const float* __restrict__ pzh,
    const float* __restrict__ pzb,
    unsigned short* __restrict__ whht, float* __restrict__ pzt,
    unsigned int* __restrict__ hbuf32, int* __restrict__ flags)
{
  int idx = blockIdx.x * 256 + threadIdx.x;
  if (idx < 65536) {  // 4*128*128
    int g = idx >> 14, r = idx & 16383, j = r >> 7, k = r & 127;
    const float* w = (g == 0) ? wih : (g == 1) ? wgh : (g == 2) ? wfh : woh;
    whht[idx] = f2bf(w[k * 128 + j]);
  }
  if (idx < 6144) {   // 3*16*128
    int r = idx & 2047, c = r >> 7, k = r & 127;
    int kind = idx >> 11;
    const float* p = (kind == 0) ? pzx : (kind == 1) ? pzh : pzb;
    pzt[idx] = p[k * 16 + c];
    (void)c; (void)k;
  }
  // zero both h buffers: [2][32][1024] tagged dwords = 65536
  __hip_atomic_store(hbuf32 + idx, 0u, __ATOMIC_RELAXED, __HIP_MEMORY_SCOPE_AGENT);
  if (idx < 3072)    // 96 flags x 32-int stride
    __hip_atomic_store(flags + idx, 0, __ATOMIC_RELAXED, __HIP_MEMORY_SCOPE_AGENT);
}

// ---------------------------------------------------------------------------
// transpose Wcat -> bf16 [n=4608][k=512]: n<4096 from Wm[:512], else Wi/g/f/o_x
// ---------------------------------------------------------------------------
__global__ __launch_bounds__(256) void k_twcat(
    const float* __restrict__ wm, const float* __restrict__ wix,
    const float* __restrict__ wgx, const float* __restrict__ wfx,
    const float* __restrict__ wox, unsigned short* __restrict__ dst)
{
  __shared__ float tile[32][33];
  int bx = blockIdx.x % 144, by = blockIdx.x / 144;
  int n0 = bx * 32, k0 = by * 32;
  int tx = threadIdx.x & 31, ty = threadIdx.x >> 5;
  #pragma unroll
  for (int i = 0; i < 4; i++) {
    int k = k0 + ty + i * 8, n = n0 + tx;
    float v;
    if (n < 4096) v = wm[(size_t)k * 4096 + n];
    else {
      int nn = n - 4096, g = nn >> 7, j = nn & 127;
      const float* w = (g == 0) ? wix : (g == 1) ? wgx : (g == 2) ? wfx : wox;
      v = w[k * 128 + j];
    }
    tile[ty + i * 8][tx] = v;
  }
  __syncthreads();
  #pragma unroll
  for (int i = 0; i < 4; i++)
    dst[(size_t)(n0 + ty + i * 8) * 512 + k0 + tx] = f2bf(tile[tx][ty + i * 8]);
}

// transpose Wm[512:] -> bf16 [n=4096][k=1024]
__global__ __launch_bounds__(256) void k_twmh(
    const float* __restrict__ wm, unsigned short* __restrict__ dst)
{
  __shared__ float tile[32][33];
  int bx = blockIdx.x % 128, by = blockIdx.x / 128;
  int n0 = bx * 32, k0 = by * 32;
  int tx = threadIdx.x & 31, ty = threadIdx.x >> 5;
  #pragma unroll
  for (int i = 0; i < 4; i++)
    tile[ty + i * 8][tx] = wm[(size_t)(512 + k0 + ty + i * 8) * 4096 + n0 + tx];
  __syncthreads();
  #pragma unroll
  for (int i = 0; i < 4; i++)
    dst[(size_t)(n0 + ty + i * 8) * 1024 + k0 + tx] = f2bf(tile[tx][ty + i * 8]);
}

// ---------------------------------------------------------------------------
// Precompute GEMM: M=16384 K=512 N=4608, bf16 MFMA, 128x128 tile, 4 waves.
// n<4096 stored block-major: n' = (jh>>4)*64 + g*16 + (jh&15)
// ---------------------------------------------------------------------------
__global__ __launch_bounds__(256) void k_gemm(
    const float* __restrict__ x, const unsigned short* __restrict__ wt,
    unsigned short* __restrict__ preall)
{
  __shared__ unsigned short la[4096];
  __shared__ unsigned short lb[4096];
  int bid = blockIdx.x;
  int mb = bid % 128, nb = bid / 128;
  int m0 = mb * 128, n0 = nb * 128;
  int tid = threadIdx.x;
  int lane = tid & 63, wid = tid >> 6;
  int wr = (wid >> 1) * 64, wc = (wid & 1) * 64;
  f4 acc[4][4] = {};
  for (int kt = 0; kt < 16; kt++) {
    int k0 = kt * 32;
    __syncthreads();
    {
      int r = tid >> 1, kh = (tid & 1) * 16;
      const float4* srcA = (const float4*)(x + (size_t)(m0 + r) * 512 + k0 + kh);
      unsigned pk[8];
      #pragma unroll
      for (int q = 0; q < 4; q++) {
        float4 f = srcA[q];
        pk[q * 2]     = (unsigned)f2bf(f.x) | ((unsigned)f2bf(f.y) << 16);
        pk[q * 2 + 1] = (unsigned)f2bf(f.z) | ((unsigned)f2bf(f.w) << 16);
      }
      int base = r * 64 + kh * 2;
      u4 v0 = {pk[0], pk[1], pk[2], pk[3]}, v1 = {pk[4], pk[5], pk[6], pk[7]};
      *(u4*)((char*)la + ((base)      ^ ((r & 7) << 4))) = v0;
      *(u4*)((char*)la + ((base + 16) ^ ((r & 7) << 4))) = v1;
    }
    {
      int r = tid >> 1, kh = (tid & 1) * 16;
      const u4* srcB = (const u4*)(wt + (size_t)(n0 + r) * 512 + k0 + kh);
      u4 v0 = srcB[0], v1 = srcB[1];
      int base = r * 64 + kh * 2;
      *(u4*)((char*)lb + ((base)      ^ ((r & 7) << 4))) = v0;
      *(u4*)((char*)lb + ((base + 16) ^ ((r & 7) << 4))) = v1;
    }
    __syncthreads();
    int fo = (lane >> 4) * 16;
    sh8 af[4], bfr[4];
    #pragma unroll
    for (int mt = 0; mt < 4; mt++) {
      int r = wr + mt * 16 + (lane & 15);
      af[mt] = *(sh8*)((char*)la + ((r * 64 + fo) ^ ((r & 7) << 4)));
    }
    #pragma unroll
    for (int nt = 0; nt < 4; nt++) {
      int r = wc + nt * 16 + (lane & 15);
      bfr[nt] = *(sh8*)((char*)lb + ((r * 64 + fo) ^ ((r & 7) << 4)));
    }
    #pragma unroll
    for (int mt = 0; mt < 4; mt++)
      #pragma unroll
      for (int nt = 0; nt < 4; nt++)
        acc[mt][nt] = __builtin_amdgcn_mfma_f32_16x16x32_bf16(af[mt], bfr[nt], acc[mt][nt], 0, 0, 0);
  }
  #pragma unroll
  for (int mt = 0; mt < 4; mt++)
    #pragma unroll
    for (int nt = 0; nt < 4; nt++) {
      f4 a = acc[mt][nt];
      #pragma unroll
      for (int rr = 0; rr < 4; rr++) {
        int m = m0 + wr + mt * 16 + (lane >> 4) * 4 + rr;
        int n = n0 + wc + nt * 16 + (lane & 15);
        int b = m >> 9, t = m & 511;
        int nn;
        if (n < 4096) { int g = n >> 10, jh = n & 1023; nn = (jh >> 4) * 64 + g * 16 + (jh & 15); }
        else nn = n;
        preall[(size_t)(t * 32 + b) * NC4 + nn] = f2bf(a[rr]);
      }
    }
}

// ---------------------------------------------------------------------------
// Fused recurrence: 96 persistent blocks x 256 threads.
// Hybrid sync: speculative TAGGED pass (1 MALL RT) with R6 flag fallback.
//   blocks 0..63 : main LSTM, 16 h-cols each. wave=(kh=K-half, bh=b-half):
//                  32 loads/wave, no register reuse (R6-proven budget).
//   blocks 64..95: hyper LSTM, 1 batch row each. Tagged z chunks + zflag.
// ---------------------------------------------------------------------------
__global__ __launch_bounds__(256, 1) void k_rec(
    const unsigned short* __restrict__ preall,
    const unsigned short* __restrict__ wmht,
    const unsigned short* __restrict__ whht,
    const float* __restrict__ pzt,
    unsigned int* __restrict__ zbuf,      // [512][32][16][4] dwords {z0,z1,z2,tag}
    const float* __restrict__ pdx, const float* __restrict__ pdh,
    const float* __restrict__ pbw, const float* __restrict__ pbb,
    const float* __restrict__ bi, const float* __restrict__ bg,
    const float* __restrict__ bff, const float* __restrict__ bo,
    const float* __restrict__ lnig, const float* __restrict__ lnib,
    const float* __restrict__ lngg, const float* __restrict__ lngb,
    const float* __restrict__ lnfg, const float* __restrict__ lnfb,
    const float* __restrict__ lnog, const float* __restrict__ lnob,
    const float* __restrict__ lncg, const float* __restrict__ lncb,
    const float* __restrict__ pzxb, const float* __restrict__ pzhb,
    const float* __restrict__ pzbb,
    unsigned int* __restrict__ hbuf32,    // [2][32][1024] tagged dwords (bf16<<16 | t)
    float* __restrict__ out,
    int* __restrict__ flags)              // [96] x 32-int stride: 0..63 h, 64..95 z
{
  __shared__ __align__(16) unsigned short wlds[64 * 1024];   // 128KB / hyper scratch
  __shared__ float red[2][32][68];
  __shared__ __align__(16) float zl[32 * 48];
  __shared__ float clds[512];
  __shared__ __align__(16) unsigned wxl[32][32];
  __shared__ float pdl[3][4][16];
  __shared__ float pbbl[16];

  const int tid = threadIdx.x;
  const int lane = tid & 63, wid = tid >> 6;

  if (blockIdx.x >= 64) {
    // =============== HYPER ROLE (b = blockIdx.x - 64) =====================
    float* const hyp  = (float*)wlds;
    float* const pzl  = hyp;          // 48*132 floats
    float* const hhs  = hyp + 6400;   // 128
    float* const chs  = hyp + 6528;   // 128
    float* const actl = hyp + 6656;   // 4*128
    float* const rwav = hyp + 7168;   // 16
    float* const redc = hyp + 7184;   // 4
    float* const zsl  = hyp + 7200;   // 48

    const int b = blockIdx.x - 64;
    const int j = tid & 127, gp = tid >> 7;
    const int ga = gp, gb = gp + 2;

    u4 wa[16], wb[16];
    {
      const u4* s = (const u4*)(whht + (size_t)(ga * 128 + j) * 128);
      #pragma unroll
      for (int i = 0; i < 16; i++) wa[i] = s[i];
      const u4* s2 = (const u4*)(whht + (size_t)(gb * 128 + j) * 128);
      #pragma unroll
      for (int i = 0; i < 16; i++) wb[i] = s2[i];
    }
    for (int i = tid; i < 6144; i += 256)
      pzl[(i >> 7) * 132 + (i & 127)] = pzt[i];

    const float* bias_p[4] = {bi, bg, bff, bo};
    const float* lng_p[4]  = {lnig, lngg, lnfg, lnog};
    const float* lnb_p[4]  = {lnib, lngb, lnfb, lnob};
    float bias_a = bias_p[ga][j], bias_b = bias_p[gb][j];
    float lgam_a = lng_p[ga][j],  lbet_a = lnb_p[ga][j];
    float lgam_b = lng_p[gb][j],  lbet_b = lnb_p[gb][j];
    float lcg = 0.f, lcb = 0.f;
    if (tid < 128) { lcg = lncg[j]; lcb = lncb[j]; hhs[j] = 0.f; chs[j] = 0.f; }
    float zbias = 0.f;
    if (tid < 48) {
      int kind = tid >> 4, c = tid & 15;
      zbias = ((kind == 0) ? pzxb : (kind == 1) ? pzhb : pzbb)[c];
    }
    __syncthreads();

    const f4* h4 = (const f4*)hhs;
    for (int t = 0; t < NT; t++) {
      float xa = bf2f(preall[(size_t)(t * 32 + b) * NC4 + 4096 + ga * 128 + j]);
      float xb = bf2f(preall[(size_t)(t * 32 + b) * NC4 + 4096 + gb * 128 + j]);
      float sa = bias_a, sb = bias_b;
      #pragma unroll
      for (int i = 0; i < 16; i++) {
        f4 h0 = h4[2 * i], h1 = h4[2 * i + 1];
        u4 w = wa[i];
        sa += blo(w.x) * h0[0] + bhi(w.x) * h0[1] + blo(w.y) * h0[2] + bhi(w.y) * h0[3]
            + blo(w.z) * h1[0] + bhi(w.z) * h1[1] + blo(w.w) * h1[2] + bhi(w.w) * h1[3];
        w = wb[i];
        sb += blo(w.x) * h0[0] + bhi(w.x) * h0[1] + blo(w.y) * h0[2] + bhi(w.y) * h0[3]
            + blo(w.z) * h1[0] + bhi(w.z) * h1[1] + blo(w.w) * h1[2] + bhi(w.w) * h1[3];
      }
      sa += xa; sb += xb;
      float a1 = sa, a2 = sa * sa, b1 = sb, b2 = sb * sb;
      #pragma unroll
      for (int m = 1; m < 64; m <<= 1) {
        a1 += __shfl_xor(a1, m); a2 += __shfl_xor(a2, m);
        b1 += __shfl_xor(b1, m); b2 += __shfl_xor(b2, m);
      }
      if ((tid & 63) == 0) {
        int w = tid >> 6;
        rwav[w * 4] = a1; rwav[w * 4 + 1] = a2; rwav[w * 4 + 2] = b1; rwav[w * 4 + 3] = b2;
      }
      __syncthreads();
      int w0 = gp * 2, w1 = gp * 2 + 1;
      float sum_a = rwav[w0 * 4] + rwav[w1 * 4],         sq_a = rwav[w0 * 4 + 1] + rwav[w1 * 4 + 1];
      float sum_b = rwav[w0 * 4 + 2] + rwav[w1 * 4 + 2], sq_b = rwav[w0 * 4 + 3] + rwav[w1 * 4 + 3];
      float mean_a = sum_a * 0.0078125f, var_a = sq_a * 0.0078125f - mean_a * mean_a;
      float mean_b = sum_b * 0.0078125f, var_b = sq_b * 0.0078125f - mean_b * mean_b;
      float xn_a = (sa - mean_a) * rsqrtf(var_a + 1e-5f) * lgam_a + lbet_a;
      float xn_b = (sb - mean_b) * rsqrtf(var_b + 1e-5f) * lgam_b + lbet_b;
      float act_a = (ga == 1) ? tanhf(xn_a) : 1.f / (1.f + __expf(-xn_a));
      float act_b = 1.f / (1.f + __expf(-xn_b));
      actl[ga * 128 + j] = act_a;
      actl[gb * 128 + j] = act_b;
      __syncthreads();
      if (tid < 128) {
        float cn = actl[2 * 128 + j] * chs[j] + actl[j] * actl[128 + j];
        chs[j] = cn;
        float c1 = cn, c2 = cn * cn;
        #pragma unroll
        for (int m = 1; m < 64; m <<= 1) { c1 += __shfl_xor(c1, m); c2 += __shfl_xor(c2, m); }
        if ((tid & 63) == 0) { int w = tid >> 6; redc[w * 2] = c1; redc[w * 2 + 1] = c2; }
      }
      __syncthreads();
      if (tid < 128) {
        float sum2 = redc[0] + redc[2], sq2 = redc[1] + redc[3];
        float mean2 = sum2 * 0.0078125f, var2 = sq2 * 0.0078125f - mean2 * mean2;
        hhs[j] = actl[3 * 128 + j] * tanhf((chs[j] - mean2) * rsqrtf(var2 + 1e-5f) * lcg + lcb);
      }
      __syncthreads();
      if (tid < 48) {   // z = hh_new @ pz*_w + pz*_b -> LDS
        const f4* pr = (const f4*)(pzl + tid * 132);
        float zv = zbias;
        #pragma unroll 8
        for (int q = 0; q < 32; q++) {
          f4 p = pr[q], hv = h4[q];
          zv += p[0] * hv[0] + p[1] * hv[1] + p[2] * hv[2] + p[3] * hv[3];
        }
        zsl[tid] = zv;
      }
      __syncthreads();
      if (tid < 16) {   // tagged chunk {z0,z1,z2,tag}: values, wave drain, tag
        unsigned* dst = zbuf + (size_t)(t * 32 + b) * 64 + tid * 4;
        __hip_atomic_store(dst + 0, asu(zsl[tid * 3 + 0]), __ATOMIC_RELAXED, __HIP_MEMORY_SCOPE_AGENT);
        __hip_atomic_store(dst + 1, asu(zsl[tid * 3 + 1]), __ATOMIC_RELAXED, __HIP_MEMORY_SCOPE_AGENT);
        __hip_atomic_store(dst + 2, asu(zsl[tid * 3 + 2]), __ATOMIC_RELAXED, __HIP_MEMORY_SCOPE_AGENT);
        asm volatile("s_waitcnt vmcnt(0)" ::: "memory");
        __hip_atomic_store(dst + 3, (unsigned)(t + 1), __ATOMIC_RELAXED, __HIP_MEMORY_SCOPE_AGENT);
      }
      asm volatile("s_waitcnt vmcnt(0)" ::: "memory");
      __syncthreads();   // all tag stores drained; protects zsl/actl/hhs
      if (tid == 0)
        __hip_atomic_store(flags + (64 + b) * 32, t + 1, __ATOMIC_RELAXED,
                           __HIP_MEMORY_SCOPE_AGENT);
    }
    return;
  }

  // ================= MAIN ROLE (blockIdx.x < 64) ==========================
  const int jh0 = blockIdx.x * 16;

  {   // stage weight slice once
    int n = tid >> 2, kc = (tid & 3) * 256;
    int g = n >> 4, jo = n & 15;
    const unsigned short* src = wmht + (size_t)(g * NH + jh0 + jo) * NH + kc;
    #pragma unroll
    for (int i = 0; i < 32; i++) {
      sh8 v = *(const sh8*)(src + i * 8);
      int byte = n * 2048 + (kc + i * 8) * 2;
      *(sh8*)((char*)wlds + (byte ^ ((n & 7) << 4))) = v;
    }
  }
  clds[tid] = 0.f; clds[tid + 256] = 0.f;
  if (tid < 192) {
    int kind = tid >> 6, e = (tid >> 4) & 3, jo = tid & 15;
    const float* p = (kind == 0) ? pdx : (kind == 1) ? pdh : pbw;
    pdl[kind][e][jo] = p[e * NH + jh0 + jo];
  }
  if (tid < 16) pbbl[tid] = pbb[jh0 + tid];
  __syncthreads();

  const int bq = tid >> 3;        // combine row b: 0..31
  const int joB = (tid & 7) * 2;  // combine adjacent col pair
  const int kh = wid >> 1;        // K-half
  const int bh = wid & 1;         // b-half
  const int col = lane & 15;
  const int koff = (lane >> 4) * 8;   // k offset (1 dword = 1 col)
  const int row = bh * 16 + col;      // the b-row this wave loads

#define HL(i, OA, OB) LD16(hA[2*(i)], bp, OA); LD16(hA[2*(i)+1], bp, OB)

#define PROCK(ks)                                                              \
  {                                                                            \
    u4 q0 = hA[2*(ks)], q1 = hA[2*(ks)+1];                                     \
    err |= (q0.x^tagh)|(q0.y^tagh)|(q0.z^tagh)|(q0.w^tagh);                    \
    err |= (q1.x^tagh)|(q1.y^tagh)|(q1.z^tagh)|(q1.w^tagh);                    \
    union { u4 u; sh8 s; } A;                                                  \
    A.u.x = __builtin_amdgcn_perm(q0.y, q0.x, 0x07060302u);                    \
    A.u.y = __builtin_amdgcn_perm(q0.w, q0.z, 0x07060302u);                    \
    A.u.z = __builtin_amdgcn_perm(q1.y, q1.x, 0x07060302u);                    \
    A.u.w = __builtin_amdgcn_perm(q1.w, q1.z, 0x07060302u);                    \
    int kb = kh * 512 + (ks) * 32 + koff;                                      \
    int n0i = col, n1i = 16 + col, n2i = 32 + col, n3i = 48 + col;             \
    sh8 b0 = *(sh8*)((char*)wlds + ((n0i * 2048 + kb * 2) ^ ((n0i & 7) << 4)));\
    sh8 b1 = *(sh8*)((char*)wlds + ((n1i * 2048 + kb * 2) ^ ((n1i & 7) << 4)));\
    sh8 b2 = *(sh8*)((char*)wlds + ((n2i * 2048 + kb * 2) ^ ((n2i & 7) << 4)));\
    sh8 b3 = *(sh8*)((char*)wlds + ((n3i * 2048 + kb * 2) ^ ((n3i & 7) << 4)));\
    acc0 = __builtin_amdgcn_mfma_f32_16x16x32_bf16(A.s, b0, acc0, 0, 0, 0);    \
    acc1 = __builtin_amdgcn_mfma_f32_16x16x32_bf16(A.s, b1, acc1, 0, 0, 0);    \
    acc2 = __builtin_amdgcn_mfma_f32_16x16x32_bf16(A.s, b2, acc2, 0, 0, 0);    \
    acc3 = __builtin_amdgcn_mfma_f32_16x16x32_bf16(A.s, b3, acc3, 0, 0, 0);    \
  }

  for (int t = 0; t < NT; t++) {
    // ---- stage wx slab (cached, block-major preall) ----------------------
    {
      const u4* s = (const u4*)(preall + (size_t)(t * 32 + bq) * NC4
                                + (size_t)blockIdx.x * 64 + (tid & 7) * 8);
      *(u4*)&wxl[bq][(tid & 7) * 4] = *s;
    }
    const unsigned tagh = (unsigned)t;
    const unsigned tagz = (unsigned)(t + 1);
    const unsigned* bp  = hbuf32 + (t & 1) * (NB * NH) + row * 1024 + kh * 512 + koff;
    const unsigned* zpb = zbuf + (size_t)t * 2048 + tid * 8;

    f4 acc0, acc1, acc2, acc3;
    for (int attempt = 0;; attempt++) {
      acc0 = acc1 = acc2 = acc3 = (f4){0.f, 0.f, 0.f, 0.f};
      unsigned err = 0;
      u4 hA[32], Z0, Z1;
      HL(0,  "0",    "16");   HL(1,  "128",  "144");
      HL(2,  "256",  "272");  HL(3,  "384",  "400");
      HL(4,  "512",  "528");  HL(5,  "640",  "656");
      HL(6,  "768",  "784");  HL(7,  "896",  "912");
      HL(8,  "1024", "1040"); HL(9,  "1152", "1168");
      HL(10, "1280", "1296"); HL(11, "1408", "1424");
      HL(12, "1536", "1552"); HL(13, "1664", "1680");
      HL(14, "1792", "1808"); HL(15, "1920", "1936");
      LD16(Z0, zpb, "0"); LD16(Z1, zpb, "16");
      asm volatile("s_waitcnt vmcnt(0)" ::: "memory");
      __builtin_amdgcn_sched_barrier(0);
      PROCK(0);  PROCK(1);  PROCK(2);  PROCK(3);
      PROCK(4);  PROCK(5);  PROCK(6);  PROCK(7);
      PROCK(8);  PROCK(9);  PROCK(10); PROCK(11);
      PROCK(12); PROCK(13); PROCK(14); PROCK(15);
      err |= (Z0.w ^ tagz) | (Z1.w ^ tagz);
      {   // stage z into LDS (final pass's values are the accepted ones)
        int zb = tid >> 3, zc = (tid & 7) * 6;
        float* zd = zl + zb * 48 + zc;
        zd[0] = asf(Z0.x); zd[1] = asf(Z0.y); zd[2] = asf(Z0.z);
        zd[3] = asf(Z1.x); zd[4] = asf(Z1.y); zd[5] = asf(Z1.z);
      }
      int okv = __all((err & 0xFFFFu) == 0);
      if (okv || attempt == 1) break;   // accept 2nd pass (flag-guaranteed)
      // ---- fallback: R6 flag wait (per wave), then one re-pass -----------
      for (;;) {
        int vh = (lane == blockIdx.x) ? t :
                 __hip_atomic_load(flags + lane * 32, __ATOMIC_RELAXED,
                                   __HIP_MEMORY_SCOPE_AGENT);
        int ok2 = (vh >= t);
        if (lane < 32) {
          int vz = __hip_atomic_load(flags + (64 + lane) * 32, __ATOMIC_RELAXED,
                                     __HIP_MEMORY_SCOPE_AGENT);
          ok2 = ok2 && (vz >= t + 1);
        }
        if (__all(ok2)) break;
        __builtin_amdgcn_s_sleep(2);
      }
    }
    // ---- red writes ------------------------------------------------------
    {
      int r0 = (lane >> 4) * 4;
      #pragma unroll
      for (int rr = 0; rr < 4; rr++) {
        red[kh][bh * 16 + r0 + rr][col]      = acc0[rr];
        red[kh][bh * 16 + r0 + rr][16 + col] = acc1[rr];
        red[kh][bh * 16 + r0 + rr][32 + col] = acc2[rr];
        red[kh][bh * 16 + r0 + rr][48 + col] = acc3[rr];
      }
    }
    __syncthreads();
    // ---- combine: thread (bq, joB) handles adjacent jo = joB, joB+1 ------
    {
      const float* zb_ = zl + bq * 48;
      const unsigned short* wxp = (const unsigned short*)&wxl[bq][0];
      float hn2[2], cn2[2];
      #pragma unroll
      for (int half = 0; half < 2; half++) {
        int jo = joB + half;
        float gv[4];
        #pragma unroll
        for (int g = 0; g < 4; g++) {
          float wh = red[0][bq][g * 16 + jo] + red[1][bq][g * 16 + jo];
          float dxv = 0.f, dhv = 0.f, bdv = pbbl[jo];
          #pragma unroll
          for (int e = 0; e < 4; e++) {
            dxv += zb_[g * 4 + e]      * pdl[0][e][jo];
            dhv += zb_[16 + g * 4 + e] * pdl[1][e][jo];
            bdv += zb_[32 + g * 4 + e] * pdl[2][e][jo];
          }
          float wxv = bf2f(wxp[g * 16 + jo]);
          gv[g] = wxv * dxv + wh * dhv + bdv;
        }
        float iv = 1.f / (1.f + __expf(-gv[0]));
        float fv = 1.f / (1.f + __expf(-gv[1]));
        float ov = 1.f / (1.f + __expf(-gv[2]));
        float gg = tanhf(gv[3]);
        int ci = bq * 16 + jo;
        float cn = fv * clds[ci] + iv * gg;
        clds[ci] = cn;
        hn2[half] = ov * tanhf(cn);
        cn2[half] = cn;
      }
      *(float2*)&out[(size_t)(bq * NT + t) * NH + jh0 + joB] = make_float2(hn2[0], hn2[1]);
      // publish h(t+1): tagged dwords (tag carried in-value; atomic per dword)
      unsigned d0 = ((unsigned)f2bf(hn2[0]) << 16) | (unsigned)(t + 1);
      unsigned d1 = ((unsigned)f2bf(hn2[1]) << 16) | (unsigned)(t + 1);
      unsigned* hd = hbuf32 + ((t + 1) & 1) * (NB * NH) + bq * 1024 + jh0 + joB;
      __hip_atomic_store(hd + 0, d0, __ATOMIC_RELAXED, __HIP_MEMORY_SCOPE_AGENT);
      __hip_atomic_store(hd + 1, d1, __ATOMIC_RELAXED, __HIP_MEMORY_SCOPE_AGENT);
      if (t == NT - 1) {
        *(float2*)&out[(size_t)NB * NT * NH + bq * NH + jh0 + joB] = make_float2(hn2[0], hn2[1]);
        *(float2*)&out[(size_t)NB * NT * NH + NB * NH + bq * NH + jh0 + joB] = make_float2(cn2[0], cn2[1]);
      }
    }
    // ---- R6 tail: drain + barrier + flag (for the fallback path) ---------
    asm volatile("s_waitcnt vmcnt(0)" ::: "memory");
    __syncthreads();   // all waves drained; protects red/zl/wxl/clds
    if (tid == 0)
      __hip_atomic_store(flags + blockIdx.x * 32, t + 1, __ATOMIC_RELAXED,
                         __HIP_MEMORY_SCOPE_AGENT);
  }
#undef HL
#undef PROCK
}

// ---------------------------------------------------------------------------
extern "C" void kernel_launch(void* const* d_in, const int* in_sizes, int n_in,
                              void* d_out, int out_size, void* d_ws, size_t ws_size,
                              hipStream_t stream) {
  (void)in_sizes; (void)n_in; (void)out_size;
  const float* x    = (const float*)d_in[0];
  const float* Wm   = (const float*)d_in[1];
  const float* Wih  = (const float*)d_in[2];
  const float* Wix  = (const float*)d_in[3];
  const float* bi   = (const float*)d_in[4];
  const float* Wgh  = (const float*)d_in[5];
  const float* Wgx  = (const float*)d_in[6];
  const float* bg   = (const float*)d_in[7];
  const float* Wfh  = (const float*)d_in[8];
  const float* Wfx  = (const float*)d_in[9];
  const float* bfp  = (const float*)d_in[10];
  const float* Woh  = (const float*)d_in[11];
  const float* Wox  = (const float*)d_in[12];
  const float* bo   = (const float*)d_in[13];
  const float* lnig = (const float*)d_in[14];
  const float* lnib = (const float*)d_in[15];
  const float* lngg = (const float*)d_in[16];
  const float* lngb = (const float*)d_in[17];
  const float* lnfg = (const float*)d_in[18];
  const float* lnfb = (const float*)d_in[19];
  const float* lnog = (const float*)d_in[20];
  const float* lnob = (const float*)d_in[21];
  const float* lncg = (const float*)d_in[22];
  const float* lncb = (const float*)d_in[23];
  const float* pzxw = (const float*)d_in[24];
  const float* pzxb = (const float*)d_in[25];
  const float* pzhw = (const float*)d_in[26];
  const float* pzhb = (const float*)d_in[27];
  const float* pzbw = (const float*)d_in[28];
  const float* pzbb = (const float*)d_in[29];
  const float* pdx  = (const float*)d_in[30];
  const float* pdh  = (const float*)d_in[31];
  const float* pbw  = (const float*)d_in[32];
  const float* pbb  = (const float*)d_in[33];
  float* out = (float*)d_out;

  char* ws = (char*)d_ws;
  size_t off = 0;
  auto alloc = [&](size_t bytes) {
    char* p = ws + off; off += (bytes + 255) & ~(size_t)255; return p;
  };
  unsigned short* preall = (unsigned short*)alloc((size_t)16384 * NC4 * 2);
  unsigned short* wcat   = (unsigned short*)alloc((size_t)NC4 * 512 * 2);
  unsigned short* wmht   = (unsigned short*)alloc((size_t)4096 * 1024 * 2);
  unsigned short* whht   = (unsigned short*)alloc((size_t)4 * 128 * 128 * 2);
  float* pzt             = (float*)alloc((size_t)3 * 16 * 128 * 4);
  unsigned int* zbuf     = (unsigned int*)alloc((size_t)NT * NB * 64 * 4);
  unsigned int* hbuf32   = (unsigned int*)alloc((size_t)2 * NB * NH * 4);
  int* flags             = (int*)alloc((size_t)96 * 32 * 4);
  if (off > ws_size) return;  // ws too small: leave output untouched (diagnosable)

  k_prep<<<256, 256, 0, stream>>>(Wih, Wgh, Wfh, Woh, pzxw, pzhw, pzbw, whht, pzt, hbuf32, flags);
  k_twcat<<<2304, 256, 0, stream>>>(Wm, Wix, Wgx, Wfx, Wox, wcat);
  k_twmh<<<4096, 256, 0, stream>>>(Wm, wmht);
  k_gemm<<<4608, 256, 0, stream>>>(x, wcat, preall);
  k_rec<<<96, 256, 0, stream>>>(preall, wmht, whht, pzt, zbuf,
      pdx, pdh, pbw, pbb, bi, bg, bfp, bo,
      lnig, lnib, lngg, lngb, lnfg, lnfb, lnog, lnob, lncg, lncb,
      pzxb, pzhb, pzbb, hbuf32, out, flags);
}

// Round 10
// 4375.901 us; speedup vs baseline: 1.1305x; 1.1305x over previous
//
#include <hip/hip_runtime.h>
#include <cstdint>
#include <cstddef>

#define NB 32       // batch
#define NT 512      // time steps
#define ND 512      // input dim D
#define NH 1024     // hidden H
#define NC4 4608    // 4H + 4*HH (fused GEMM N)

typedef short sh8 __attribute__((ext_vector_type(8)));   // 8 bf16 (raw bits)
typedef float f4  __attribute__((ext_vector_type(4)));
typedef unsigned int u4 __attribute__((ext_vector_type(4)));

__device__ __forceinline__ unsigned short f2bf(float x) {
  union { float f; unsigned u; } v; v.f = x;
  unsigned r = v.u + 0x7FFFu + ((v.u >> 16) & 1u);   // RNE
  return (unsigned short)(r >> 16);
}
__device__ __forceinline__ float bf2f(unsigned short b) {
  union { unsigned u; float f; } v; v.u = ((unsigned)b) << 16; return v.f;
}
__device__ __forceinline__ float blo(unsigned w) { union { unsigned u; float f; } v; v.u = w << 16; return v.f; }
__device__ __forceinline__ float bhi(unsigned w) { union { unsigned u; float f; } v; v.u = w & 0xFFFF0000u; return v.f; }

// MALL-coherent 16B load: bypasses L1/L2 (sc0 sc1).
#define LD16(dst, base, OFFSTR)                                         \
  asm volatile("global_load_dwordx4 %0, %1, off offset:" OFFSTR " sc0 sc1" \
               : "=v"(dst) : "v"(base))

// ---------------------------------------------------------------------------
// prep: hyper gate weights -> bf16 transposed; pz weights -> fp32 transposed;
//       zero h buf0 (packed bf16 pairs); zero 96 flag lines
// ---------------------------------------------------------------------------
__global__ __launch_bounds__(256) void k_prep(
    const float* __restrict__ wih, const float* __restrict__ wgh,
    const float* __restrict__ wfh, const float* __restrict__ woh,
    const float* __restrict__ pzx, const float* __restrict__ pzh,
    const float* __restrict__ pzb,
    unsigned short* __restrict__ whht, float* __restrict__ pzt,
    unsigned int* __restrict__ hbuf32, int* __restrict__ flags)
{
  int idx = blockIdx.x * 256 + threadIdx.x;
  if (idx < 65536) {  // 4*128*128
    int g = idx >> 14, r = idx & 16383, j = r >> 7, k = r & 127;
    const float* w = (g == 0) ? wih : (g == 1) ? wgh : (g == 2) ? wfh : woh;
    whht[idx] = f2bf(w[k * 128 + j]);
  }
  if (idx < 6144) {   // 3*16*128
    int r = idx & 2047, c = r >> 7, k = r & 127;
    int kind = idx >> 11;
    const float* p = (kind == 0) ? pzx : (kind == 1) ? pzh : pzb;
    pzt[idx] = p[k * 16 + c];
    (void)c; (void)k;
  }
  if (idx < 16384)   // zero buf0 (32*1024 bf16 packed as 16384 dwords)
    __hip_atomic_store(hbuf32 + idx, 0u, __ATOMIC_RELAXED, __HIP_MEMORY_SCOPE_AGENT);
  if (idx < 3072)    // 96 flags x 32-int stride
    __hip_atomic_store(flags + idx, 0, __ATOMIC_RELAXED, __HIP_MEMORY_SCOPE_AGENT);
}

// ---------------------------------------------------------------------------
// transpose Wcat -> bf16 [n=4608][k=512]: n<4096 from Wm[:512], else Wi/g/f/o_x
// ---------------------------------------------------------------------------
__global__ __launch_bounds__(256) void k_twcat(
    const float* __restrict__ wm, const float* __restrict__ wix,
    const float* __restrict__ wgx, const float* __restrict__ wfx,
    const float* __restrict__ wox, unsigned short* __restrict__ dst)
{
  __shared__ float tile[32][33];
  int bx = blockIdx.x % 144, by = blockIdx.x / 144;
  int n0 = bx * 32, k0 = by * 32;
  int tx = threadIdx.x & 31, ty = threadIdx.x >> 5;
  #pragma unroll
  for (int i = 0; i < 4; i++) {
    int k = k0 + ty + i * 8, n = n0 + tx;
    float v;
    if (n < 4096) v = wm[(size_t)k * 4096 + n];
    else {
      int nn = n - 4096, g = nn >> 7, j = nn & 127;
      const float* w = (g == 0) ? wix : (g == 1) ? wgx : (g == 2) ? wfx : wox;
      v = w[k * 128 + j];
    }
    tile[ty + i * 8][tx] = v;
  }
  __syncthreads();
  #pragma unroll
  for (int i = 0; i < 4; i++)
    dst[(size_t)(n0 + ty + i * 8) * 512 + k0 + tx] = f2bf(tile[tx][ty + i * 8]);
}

// transpose Wm[512:] -> bf16 [n=4096][k=1024]
__global__ __launch_bounds__(256) void k_twmh(
    const float* __restrict__ wm, unsigned short* __restrict__ dst)
{
  __shared__ float tile[32][33];
  int bx = blockIdx.x % 128, by = blockIdx.x / 128;
  int n0 = bx * 32, k0 = by * 32;
  int tx = threadIdx.x & 31, ty = threadIdx.x >> 5;
  #pragma unroll
  for (int i = 0; i < 4; i++)
    tile[ty + i * 8][tx] = wm[(size_t)(512 + k0 + ty + i * 8) * 4096 + n0 + tx];
  __syncthreads();
  #pragma unroll
  for (int i = 0; i < 4; i++)
    dst[(size_t)(n0 + ty + i * 8) * 1024 + k0 + tx] = f2bf(tile[tx][ty + i * 8]);
}

// ---------------------------------------------------------------------------
// Precompute GEMM: M=16384 K=512 N=4608, bf16 MFMA, 128x128 tile, 4 waves.
// n<4096 stored block-major: n' = (jh>>4)*64 + g*16 + (jh&15)
// ---------------------------------------------------------------------------
__global__ __launch_bounds__(256) void k_gemm(
    const float* __restrict__ x, const unsigned short* __restrict__ wt,
    unsigned short* __restrict__ preall)
{
  __shared__ unsigned short la[4096];
  __shared__ unsigned short lb[4096];
  int bid = blockIdx.x;
  int mb = bid % 128, nb = bid / 128;
  int m0 = mb * 128, n0 = nb * 128;
  int tid = threadIdx.x;
  int lane = tid & 63, wid = tid >> 6;
  int wr = (wid >> 1) * 64, wc = (wid & 1) * 64;
  f4 acc[4][4] = {};
  for (int kt = 0; kt < 16; kt++) {
    int k0 = kt * 32;
    __syncthreads();
    {
      int r = tid >> 1, kh = (tid & 1) * 16;
      const float4* srcA = (const float4*)(x + (size_t)(m0 + r) * 512 + k0 + kh);
      unsigned pk[8];
      #pragma unroll
      for (int q = 0; q < 4; q++) {
        float4 f = srcA[q];
        pk[q * 2]     = (unsigned)f2bf(f.x) | ((unsigned)f2bf(f.y) << 16);
        pk[q * 2 + 1] = (unsigned)f2bf(f.z) | ((unsigned)f2bf(f.w) << 16);
      }
      int base = r * 64 + kh * 2;
      u4 v0 = {pk[0], pk[1], pk[2], pk[3]}, v1 = {pk[4], pk[5], pk[6], pk[7]};
      *(u4*)((char*)la + ((base)      ^ ((r & 7) << 4))) = v0;
      *(u4*)((char*)la + ((base + 16) ^ ((r & 7) << 4))) = v1;
    }
    {
      int r = tid >> 1, kh = (tid & 1) * 16;
      const u4* srcB = (const u4*)(wt + (size_t)(n0 + r) * 512 + k0 + kh);
      u4 v0 = srcB[0], v1 = srcB[1];
      int base = r * 64 + kh * 2;
      *(u4*)((char*)lb + ((base)      ^ ((r & 7) << 4))) = v0;
      *(u4*)((char*)lb + ((base + 16) ^ ((r & 7) << 4))) = v1;
    }
    __syncthreads();
    int fo = (lane >> 4) * 16;
    sh8 af[4], bfr[4];
    #pragma unroll
    for (int mt = 0; mt < 4; mt++) {
      int r = wr + mt * 16 + (lane & 15);
      af[mt] = *(sh8*)((char*)la + ((r * 64 + fo) ^ ((r & 7) << 4)));
    }
    #pragma unroll
    for (int nt = 0; nt < 4; nt++) {
      int r = wc + nt * 16 + (lane & 15);
      bfr[nt] = *(sh8*)((char*)lb + ((r * 64 + fo) ^ ((r & 7) << 4)));
    }
    #pragma unroll
    for (int mt = 0; mt < 4; mt++)
      #pragma unroll
      for (int nt = 0; nt < 4; nt++)
        acc[mt][nt] = __builtin_amdgcn_mfma_f32_16x16x32_bf16(af[mt], bfr[nt], acc[mt][nt], 0, 0, 0);
  }
  #pragma unroll
  for (int mt = 0; mt < 4; mt++)
    #pragma unroll
    for (int nt = 0; nt < 4; nt++) {
      f4 a = acc[mt][nt];
      #pragma unroll
      for (int rr = 0; rr < 4; rr++) {
        int m = m0 + wr + mt * 16 + (lane >> 4) * 4 + rr;
        int n = n0 + wc + nt * 16 + (lane & 15);
        int b = m >> 9, t = m & 511;
        int nn;
        if (n < 4096) { int g = n >> 10, jh = n & 1023; nn = (jh >> 4) * 64 + g * 16 + (jh & 15); }
        else nn = n;
        preall[(size_t)(t * 32 + b) * NC4 + nn] = f2bf(a[rr]);
      }
    }
}

// ---------------------------------------------------------------------------
// Fused recurrence: 96 persistent blocks x 256 threads, R6 flag protocol.
//   blocks 0..63 : main LSTM, 16 h-cols each.
//     waves 0,1: 16 b-rows each x full K -> in-register combine (no red LDS,
//                c in VGPR); h loads 32 x LD16/lane (no duplication).
//     waves 2,3: service pipe — poll z-flags, stage zl+wxl concurrently.
//   blocks 64..95: hyper LSTM, 1 batch row each (R6 verbatim).
// ---------------------------------------------------------------------------
__global__ __launch_bounds__(256, 1) void k_rec(
    const unsigned short* __restrict__ preall,
    const unsigned short* __restrict__ wmht,
    const unsigned short* __restrict__ whht,
    const float* __restrict__ pzt,
    float* __restrict__ zbuf,             // [512][32][48] fp32
    const float* __restrict__ pdx, const float* __restrict__ pdh,
    const float* __restrict__ pbw, const float* __restrict__ pbb,
    const float* __restrict__ bi, const float* __restrict__ bg,
    const float* __restrict__ bff, const float* __restrict__ bo,
    const float* __restrict__ lnig, const float* __restrict__ lnib,
    const float* __restrict__ lngg, const float* __restrict__ lngb,
    const float* __restrict__ lnfg, const float* __restrict__ lnfb,
    const float* __restrict__ lnog, const float* __restrict__ lnob,
    const float* __restrict__ lncg, const float* __restrict__ lncb,
    const float* __restrict__ pzxb, const float* __restrict__ pzhb,
    const float* __restrict__ pzbb,
    unsigned int* __restrict__ hbuf32,    // [2][32][512] u32 (bf16 pairs) ping-pong
    float* __restrict__ out,
    int* __restrict__ flags)              // [96] x 32-int stride: 0..63 h, 64..95 z
{
  __shared__ __align__(16) unsigned short wlds[64 * 1024];   // 128KB / hyper scratch
  __shared__ __align__(16) float zl[32 * 52];                // padded rows
  __shared__ __align__(16) unsigned short wxl[32 * 72];      // padded rows
  __shared__ __align__(16) float pdl[3][16][4];              // [kind][jo][e]
  __shared__ float pbbl[16];

  const int tid = threadIdx.x;
  const int lane = tid & 63, wid = tid >> 6;

  if (blockIdx.x >= 64) {
    // =============== HYPER ROLE (b = blockIdx.x - 64) — R6 verbatim =======
    float* const hyp  = (float*)wlds;
    float* const pzl  = hyp;          // 48*132 floats
    float* const hhs  = hyp + 6400;   // 128
    float* const chs  = hyp + 6528;   // 128
    float* const actl = hyp + 6656;   // 4*128
    float* const rwav = hyp + 7168;   // 16
    float* const redc = hyp + 7184;   // 4

    const int b = blockIdx.x - 64;
    const int j = tid & 127, gp = tid >> 7;
    const int ga = gp, gb = gp + 2;

    u4 wa[16], wb[16];
    {
      const u4* s = (const u4*)(whht + (size_t)(ga * 128 + j) * 128);
      #pragma unroll
      for (int i = 0; i < 16; i++) wa[i] = s[i];
      const u4* s2 = (const u4*)(whht + (size_t)(gb * 128 + j) * 128);
      #pragma unroll
      for (int i = 0; i < 16; i++) wb[i] = s2[i];
    }
    for (int i = tid; i < 6144; i += 256)
      pzl[(i >> 7) * 132 + (i & 127)] = pzt[i];

    const float* bias_p[4] = {bi, bg, bff, bo};
    const float* lng_p[4]  = {lnig, lngg, lnfg, lnog};
    const float* lnb_p[4]  = {lnib, lngb, lnfb, lnob};
    float bias_a = bias_p[ga][j], bias_b = bias_p[gb][j];
    float lgam_a = lng_p[ga][j],  lbet_a = lnb_p[ga][j];
    float lgam_b = lng_p[gb][j],  lbet_b = lnb_p[gb][j];
    float lcg = 0.f, lcb = 0.f;
    if (tid < 128) { lcg = lncg[j]; lcb = lncb[j]; hhs[j] = 0.f; chs[j] = 0.f; }
    float zbias = 0.f;
    if (tid < 48) {
      int kind = tid >> 4, c = tid & 15;
      zbias = ((kind == 0) ? pzxb : (kind == 1) ? pzhb : pzbb)[c];
    }
    __syncthreads();

    const f4* h4 = (const f4*)hhs;
    for (int t = 0; t < NT; t++) {
      float xa = bf2f(preall[(size_t)(t * 32 + b) * NC4 + 4096 + ga * 128 + j]);
      float xb = bf2f(preall[(size_t)(t * 32 + b) * NC4 + 4096 + gb * 128 + j]);
      float sa = bias_a, sb = bias_b;
      #pragma unroll
      for (int i = 0; i < 16; i++) {
        f4 h0 = h4[2 * i], h1 = h4[2 * i + 1];
        u4 w = wa[i];
        sa += blo(w.x) * h0[0] + bhi(w.x) * h0[1] + blo(w.y) * h0[2] + bhi(w.y) * h0[3]
            + blo(w.z) * h1[0] + bhi(w.z) * h1[1] + blo(w.w) * h1[2] + bhi(w.w) * h1[3];
        w = wb[i];
        sb += blo(w.x) * h0[0] + bhi(w.x) * h0[1] + blo(w.y) * h0[2] + bhi(w.y) * h0[3]
            + blo(w.z) * h1[0] + bhi(w.z) * h1[1] + blo(w.w) * h1[2] + bhi(w.w) * h1[3];
      }
      sa += xa; sb += xb;
      float a1 = sa, a2 = sa * sa, b1 = sb, b2 = sb * sb;
      #pragma unroll
      for (int m = 1; m < 64; m <<= 1) {
        a1 += __shfl_xor(a1, m); a2 += __shfl_xor(a2, m);
        b1 += __shfl_xor(b1, m); b2 += __shfl_xor(b2, m);
      }
      if ((tid & 63) == 0) {
        int w = tid >> 6;
        rwav[w * 4] = a1; rwav[w * 4 + 1] = a2; rwav[w * 4 + 2] = b1; rwav[w * 4 + 3] = b2;
      }
      __syncthreads();
      int w0 = gp * 2, w1 = gp * 2 + 1;
      float sum_a = rwav[w0 * 4] + rwav[w1 * 4],         sq_a = rwav[w0 * 4 + 1] + rwav[w1 * 4 + 1];
      float sum_b = rwav[w0 * 4 + 2] + rwav[w1 * 4 + 2], sq_b = rwav[w0 * 4 + 3] + rwav[w1 * 4 + 3];
      float mean_a = sum_a * 0.0078125f, var_a = sq_a * 0.0078125f - mean_a * mean_a;
      float mean_b = sum_b * 0.0078125f, var_b = sq_b * 0.0078125f - mean_b * mean_b;
      float xn_a = (sa - mean_a) * rsqrtf(var_a + 1e-5f) * lgam_a + lbet_a;
      float xn_b = (sb - mean_b) * rsqrtf(var_b + 1e-5f) * lgam_b + lbet_b;
      float act_a = (ga == 1) ? tanhf(xn_a) : 1.f / (1.f + __expf(-xn_a));
      float act_b = 1.f / (1.f + __expf(-xn_b));
      actl[ga * 128 + j] = act_a;
      actl[gb * 128 + j] = act_b;
      __syncthreads();
      if (tid < 128) {
        float cn = actl[2 * 128 + j] * chs[j] + actl[j] * actl[128 + j];
        chs[j] = cn;
        float c1 = cn, c2 = cn * cn;
        #pragma unroll
        for (int m = 1; m < 64; m <<= 1) { c1 += __shfl_xor(c1, m); c2 += __shfl_xor(c2, m); }
        if ((tid & 63) == 0) { int w = tid >> 6; redc[w * 2] = c1; redc[w * 2 + 1] = c2; }
      }
      __syncthreads();
      if (tid < 128) {
        float sum2 = redc[0] + redc[2], sq2 = redc[1] + redc[3];
        float mean2 = sum2 * 0.0078125f, var2 = sq2 * 0.0078125f - mean2 * mean2;
        hhs[j] = actl[3 * 128 + j] * tanhf((chs[j] - mean2) * rsqrtf(var2 + 1e-5f) * lcg + lcb);
      }
      __syncthreads();
      if (tid < 48) {   // z = hh_new @ pz*_w + pz*_b -> publish via MALL store
        const f4* pr = (const f4*)(pzl + tid * 132);
        float zv = zbias;
        #pragma unroll 8
        for (int q = 0; q < 32; q++) {
          f4 p = pr[q], hv = h4[q];
          zv += p[0] * hv[0] + p[1] * hv[1] + p[2] * hv[2] + p[3] * hv[3];
        }
        union { float f; unsigned u; } cv; cv.f = zv;
        __hip_atomic_store((unsigned*)zbuf + (size_t)(t * 32 + b) * 48 + tid, cv.u,
                           __ATOMIC_RELAXED, __HIP_MEMORY_SCOPE_AGENT);
      }
      asm volatile("s_waitcnt vmcnt(0)" ::: "memory");
      __syncthreads();   // z stores drained block-wide; protects hhs/actl reuse
      if (tid == 0)
        __hip_atomic_store(flags + (64 + b) * 32, t + 1, __ATOMIC_RELAXED,
                           __HIP_MEMORY_SCOPE_AGENT);
    }
    return;
  }

  // ================= MAIN ROLE (blockIdx.x < 64) ==========================
  const int jh0 = blockIdx.x * 16;

  {   // stage weight slice once: n = g*16+jo -> wmht row g*NH + jh0 + jo
    int n = tid >> 2, kc = (tid & 3) * 256;
    int g = n >> 4, jo = n & 15;
    const unsigned short* src = wmht + (size_t)(g * NH + jh0 + jo) * NH + kc;
    #pragma unroll
    for (int i = 0; i < 32; i++) {
      sh8 v = *(const sh8*)(src + i * 8);
      int byte = n * 2048 + (kc + i * 8) * 2;
      *(sh8*)((char*)wlds + (byte ^ ((n & 7) << 4))) = v;
    }
  }
  if (tid < 192) {
    int kind = tid >> 6, e = (tid >> 4) & 3, jo = tid & 15;
    const float* p = (kind == 0) ? pdx : (kind == 1) ? pdh : pbw;
    pdl[kind][jo][e] = p[e * NH + jh0 + jo];   // transposed: [kind][jo][e]
  }
  if (tid < 16) pbbl[tid] = pbb[jh0 + tid];
  __syncthreads();

  const int col  = lane & 15;
  const int rgrp = lane >> 4;            // 0..3
  const int brow = wid * 16 + col;       // A-row this lane loads (waves 0,1)
  const int swz  = (col & 7) << 4;
  const int bbase = col * 2048 + rgrp * 16;
  const int tid2 = tid - 128;            // staging-wave index (waves 2,3)

  f4 pdx4 = {0,0,0,0}, pdh4 = {0,0,0,0}, pdb4 = {0,0,0,0};
  float pbbv = 0.f;
  if (wid < 2) {
    pdx4 = *(const f4*)&pdl[0][col][0];
    pdh4 = *(const f4*)&pdl[1][col][0];
    pdb4 = *(const f4*)&pdl[2][col][0];
    pbbv = pbbl[col];
  }
  float creg[4] = {0.f, 0.f, 0.f, 0.f};

#define HLD(i, OFF) LD16(hreg[i], bp, OFF)
#define PROCK(ks)                                                              \
  {                                                                            \
    union { u4 u; sh8 s; } A_; A_.u = hreg[ks];                                \
    _Pragma("unroll")                                                          \
    for (int g = 0; g < 4; g++) {                                              \
      sh8 bfr = *(sh8*)((char*)wlds + ((bbase + g * 32768 + (ks) * 64) ^ swz));\
      acc[g] = __builtin_amdgcn_mfma_f32_16x16x32_bf16(A_.s, bfr, acc[g], 0, 0, 0); \
    }                                                                          \
  }

  for (int t = 0; t < NT; t++) {
    f4 acc[4] = {};
    if (wid < 2) {
      // ---- poll h flags (64 producers), then load h + MFMA ---------------
      for (;;) {
        int v = (lane == blockIdx.x) ? t :
                __hip_atomic_load(flags + lane * 32, __ATOMIC_RELAXED,
                                  __HIP_MEMORY_SCOPE_AGENT);
        if (__all(v >= t)) break;
        __builtin_amdgcn_s_sleep(1);
      }
      const unsigned* bp = hbuf32 + (t & 1) * 16384 + brow * 512 + rgrp * 4;
      u4 hreg[32];
      HLD(0,  "0");    HLD(1,  "64");   HLD(2,  "128");  HLD(3,  "192");
      HLD(4,  "256");  HLD(5,  "320");  HLD(6,  "384");  HLD(7,  "448");
      HLD(8,  "512");  HLD(9,  "576");  HLD(10, "640");  HLD(11, "704");
      HLD(12, "768");  HLD(13, "832");  HLD(14, "896");  HLD(15, "960");
      HLD(16, "1024"); HLD(17, "1088"); HLD(18, "1152"); HLD(19, "1216");
      HLD(20, "1280"); HLD(21, "1344"); HLD(22, "1408"); HLD(23, "1472");
      HLD(24, "1536"); HLD(25, "1600"); HLD(26, "1664"); HLD(27, "1728");
      HLD(28, "1792"); HLD(29, "1856"); HLD(30, "1920"); HLD(31, "1984");
      asm volatile("s_waitcnt vmcnt(16)" ::: "memory");
      __builtin_amdgcn_sched_barrier(0);
      PROCK(0);  PROCK(1);  PROCK(2);  PROCK(3);
      PROCK(4);  PROCK(5);  PROCK(6);  PROCK(7);
      PROCK(8);  PROCK(9);  PROCK(10); PROCK(11);
      PROCK(12); PROCK(13); PROCK(14); PROCK(15);
      asm volatile("s_waitcnt vmcnt(0)" ::: "memory");
      __builtin_amdgcn_sched_barrier(0);
      PROCK(16); PROCK(17); PROCK(18); PROCK(19);
      PROCK(20); PROCK(21); PROCK(22); PROCK(23);
      PROCK(24); PROCK(25); PROCK(26); PROCK(27);
      PROCK(28); PROCK(29); PROCK(30); PROCK(31);
    } else {
      // ---- service pipe: poll z flags, stage zl + wxl --------------------
      for (;;) {
        int v = (lane < 32) ?
                __hip_atomic_load(flags + (64 + lane) * 32, __ATOMIC_RELAXED,
                                  __HIP_MEMORY_SCOPE_AGENT) : 0x7fffffff;
        if (__all(v >= t + 1)) break;
        __builtin_amdgcn_s_sleep(1);
      }
      const int zb = tid2 >> 2, zq = tid2 & 3;
      const unsigned* zp = (const unsigned*)zbuf + (size_t)t * 1536 + zb * 48 + zq * 12;
      u4 z0, z1, z2;
      LD16(z0, zp, "0"); LD16(z1, zp, "16"); LD16(z2, zp, "32");
      const u4* wsp = (const u4*)(preall + (size_t)(t * 32 + zb) * NC4
                                  + (size_t)blockIdx.x * 64 + zq * 16);
      u4 wv0 = wsp[0], wv1 = wsp[1];
      asm volatile("s_waitcnt vmcnt(0)" ::: "memory");
      float* zd = zl + zb * 52 + zq * 12;
      *(u4*)(zd) = z0; *(u4*)(zd + 4) = z1; *(u4*)(zd + 8) = z2;
      unsigned short* wd = wxl + zb * 72 + zq * 16;
      *(u4*)wd = wv0; *(u4*)(wd + 8) = wv1;
    }
    __syncthreads();   // barrier B: zl/wxl ready; acc ready
    if (wid < 2) {
      // ---- in-register combine: lane owns (4 rows, col=jo, all 4 gates) --
      #pragma unroll
      for (int rr = 0; rr < 4; rr++) {
        int b = wid * 16 + rgrp * 4 + rr;
        const float* zr = zl + b * 52;
        const unsigned short* wxr = wxl + b * 72;
        float gv[4];
        #pragma unroll
        for (int g = 0; g < 4; g++) {
          f4 zx = *(const f4*)(zr + g * 4);
          f4 zh = *(const f4*)(zr + 16 + g * 4);
          f4 zb4 = *(const f4*)(zr + 32 + g * 4);
          float dxv = zx[0] * pdx4[0] + zx[1] * pdx4[1] + zx[2] * pdx4[2] + zx[3] * pdx4[3];
          float dhv = zh[0] * pdh4[0] + zh[1] * pdh4[1] + zh[2] * pdh4[2] + zh[3] * pdh4[3];
          float bdv = pbbv + zb4[0] * pdb4[0] + zb4[1] * pdb4[1] + zb4[2] * pdb4[2] + zb4[3] * pdb4[3];
          gv[g] = bf2f(wxr[g * 16 + col]) * dxv + acc[g][rr] * dhv + bdv;
        }
        float iv = 1.f / (1.f + __expf(-gv[0]));
        float fv = 1.f / (1.f + __expf(-gv[1]));
        float ov = 1.f / (1.f + __expf(-gv[2]));
        float gg = tanhf(gv[3]);
        float cn = fv * creg[rr] + iv * gg;
        creg[rr] = cn;
        float hn = ov * tanhf(cn);
        out[(size_t)(b * NT + t) * NH + jh0 + col] = hn;
        float hnn = __shfl_xor(hn, 1);   // neighbor jo's value
        if (!(lane & 1)) {
          unsigned dv = (unsigned)f2bf(hn) | ((unsigned)f2bf(hnn) << 16);
          __hip_atomic_store(hbuf32 + ((t + 1) & 1) * 16384 + b * 512
                             + blockIdx.x * 8 + (col >> 1),
                             dv, __ATOMIC_RELAXED, __HIP_MEMORY_SCOPE_AGENT);
        }
        if (t == NT - 1) {
          out[(size_t)NB * NT * NH + b * NH + jh0 + col] = hn;
          out[(size_t)NB * NT * NH + NB * NH + b * NH + jh0 + col] = cn;
        }
      }
    }
    __syncthreads();   // barrier A: all stores drained (per-wave waitcnt)
    if (tid == 0)
      __hip_atomic_store(flags + blockIdx.x * 32, t + 1, __ATOMIC_RELAXED,
                         __HIP_MEMORY_SCOPE_AGENT);
  }
#undef HLD
#undef PROCK
}

// ---------------------------------------------------------------------------
extern "C" void kernel_launch(void* const* d_in, const int* in_sizes, int n_in,
                              void* d_out, int out_size, void* d_ws, size_t ws_size,
                              hipStream_t stream) {
  (void)in_sizes; (void)n_in; (void)out_size;
  const float* x    = (const float*)d_in[0];
  const float* Wm   = (const float*)d_in[1];
  const float* Wih  = (const float*)d_in[2];
  const float* Wix  = (const float*)d_in[3];
  const float* bi   = (const float*)d_in[4];
  const float* Wgh  = (const float*)d_in[5];
  const float* Wgx  = (const float*)d_in[6];
  const float* bg   = (const float*)d_in[7];
  const float* Wfh  = (const float*)d_in[8];
  const float* Wfx  = (const float*)d_in[9];
  const float* bfp  = (const float*)d_in[10];
  const float* Woh  = (const float*)d_in[11];
  const float* Wox  = (const float*)d_in[12];
  const float* bo   = (const float*)d_in[13];
  const float* lnig = (const float*)d_in[14];
  const float* lnib = (const float*)d_in[15];
  const float* lngg = (const float*)d_in[16];
  const float* lngb = (const float*)d_in[17];
  const float* lnfg = (const float*)d_in[18];
  const float* lnfb = (const float*)d_in[19];
  const float* lnog = (const float*)d_in[20];
  const float* lnob = (const float*)d_in[21];
  const float* lncg = (const float*)d_in[22];
  const float* lncb = (const float*)d_in[23];
  const float* pzxw = (const float*)d_in[24];
  const float* pzxb = (const float*)d_in[25];
  const float* pzhw = (const float*)d_in[26];
  const float* pzhb = (const float*)d_in[27];
  const float* pzbw = (const float*)d_in[28];
  const float* pzbb = (const float*)d_in[29];
  const float* pdx  = (const float*)d_in[30];
  const float* pdh  = (const float*)d_in[31];
  const float* pbw  = (const float*)d_in[32];
  const float* pbb  = (const float*)d_in[33];
  float* out = (float*)d_out;

  char* ws = (char*)d_ws;
  size_t off = 0;
  auto alloc = [&](size_t bytes) {
    char* p = ws + off; off += (bytes + 255) & ~(size_t)255; return p;
  };
  unsigned short* preall = (unsigned short*)alloc((size_t)16384 * NC4 * 2);
  unsigned short* wcat   = (unsigned short*)alloc((size_t)NC4 * 512 * 2);
  unsigned short* wmht   = (unsigned short*)alloc((size_t)4096 * 1024 * 2);
  unsigned short* whht   = (unsigned short*)alloc((size_t)4 * 128 * 128 * 2);
  float* pzt             = (float*)alloc((size_t)3 * 16 * 128 * 4);
  float* zbuf            = (float*)alloc((size_t)NT * NB * 48 * 4);
  unsigned int* hbuf32   = (unsigned int*)alloc((size_t)2 * NB * NH * 2);
  int* flags             = (int*)alloc((size_t)96 * 32 * 4);
  if (off > ws_size) return;  // ws too small: leave output untouched (diagnosable)

  k_prep<<<256, 256, 0, stream>>>(Wih, Wgh, Wfh, Woh, pzxw, pzhw, pzbw, whht, pzt, hbuf32, flags);
  k_twcat<<<2304, 256, 0, stream>>>(Wm, Wix, Wgx, Wfx, Wox, wcat);
  k_twmh<<<4096, 256, 0, stream>>>(Wm, wmht);
  k_gemm<<<4608, 256, 0, stream>>>(x, wcat, preall);
  k_rec<<<96, 256, 0, stream>>>(preall, wmht, whht, pzt, zbuf,
      pdx, pdh, pbw, pbb, bi, bg, bfp, bo,
      lnig, lnib, lngg, lngb, lnfg, lnfb, lnog, lnob, lncg, lncb,
      pzxb, pzhb, pzbb, hbuf32, out, flags);
}

// Round 11
// 4050.600 us; speedup vs baseline: 1.2213x; 1.0803x over previous
//
#include <hip/hip_runtime.h>
#include <cstdint>
#include <cstddef>

#define NB 32       // batch
#define NT 512      // time steps
#define ND 512      // input dim D
#define NH 1024     // hidden H
#define NC4 4608    // 4H + 4*HH (fused GEMM N)

typedef short sh8 __attribute__((ext_vector_type(8)));   // 8 bf16 (raw bits)
typedef float f4  __attribute__((ext_vector_type(4)));
typedef unsigned int u4 __attribute__((ext_vector_type(4)));

__device__ __forceinline__ unsigned short f2bf(float x) {
  union { float f; unsigned u; } v; v.f = x;
  unsigned r = v.u + 0x7FFFu + ((v.u >> 16) & 1u);   // RNE
  return (unsigned short)(r >> 16);
}
__device__ __forceinline__ float bf2f(unsigned short b) {
  union { unsigned u; float f; } v; v.u = ((unsigned)b) << 16; return v.f;
}
__device__ __forceinline__ float blo(unsigned w) { union { unsigned u; float f; } v; v.u = w << 16; return v.f; }
__device__ __forceinline__ float bhi(unsigned w) { union { unsigned u; float f; } v; v.u = w & 0xFFFF0000u; return v.f; }

// MALL-coherent 16B load: bypasses L1/L2 (sc0 sc1).
#define LD16(dst, base, OFFSTR)                                         \
  asm volatile("global_load_dwordx4 %0, %1, off offset:" OFFSTR " sc0 sc1" \
               : "=v"(dst) : "v"(base))

// ---------------------------------------------------------------------------
// prep: hyper gate weights -> bf16 transposed; pz weights -> fp32 transposed;
//       zero h buf0; zero 96 packed flags
// ---------------------------------------------------------------------------
__global__ __launch_bounds__(256) void k_prep(
    const float* __restrict__ wih, const float* __restrict__ wgh,
    const float* __restrict__ wfh, const float* __restrict__ woh,
    const float* __restrict__ pzx, const float* __restrict__ pzh,
    const float* __restrict__ pzb,
    unsigned short* __restrict__ whht, float* __restrict__ pzt,
    unsigned int* __restrict__ hbuf32, int* __restrict__ flags)
{
  int idx = blockIdx.x * 256 + threadIdx.x;
  if (idx < 65536) {  // 4*128*128
    int g = idx >> 14, r = idx & 16383, j = r >> 7, k = r & 127;
    const float* w = (g == 0) ? wih : (g == 1) ? wgh : (g == 2) ? wfh : woh;
    whht[idx] = f2bf(w[k * 128 + j]);
  }
  if (idx < 6144) {   // 3*16*128
    int r = idx & 2047, c = r >> 7, k = r & 127;
    int kind = idx >> 11;
    const float* p = (kind == 0) ? pzx : (kind == 1) ? pzh : pzb;
    pzt[idx] = p[k * 16 + c];
    (void)c; (void)k;
  }
  if (idx < 16384)   // zero buf0 (32*1024 bf16) via MALL so bypass-reads see it
    __hip_atomic_store(hbuf32 + idx, 0u, __ATOMIC_RELAXED, __HIP_MEMORY_SCOPE_AGENT);
  if (idx < 96)      // packed flags: [0..63] h, [64..95] z
    __hip_atomic_store(flags + idx, 0, __ATOMIC_RELAXED, __HIP_MEMORY_SCOPE_AGENT);
}

// ---------------------------------------------------------------------------
// transpose Wcat -> bf16 [n=4608][k=512]: n<4096 from Wm[:512], else Wi/g/f/o_x
// ---------------------------------------------------------------------------
__global__ __launch_bounds__(256) void k_twcat(
    const float* __restrict__ wm, const float* __restrict__ wix,
    const float* __restrict__ wgx, const float* __restrict__ wfx,
    const float* __restrict__ wox, unsigned short* __restrict__ dst)
{
  __shared__ float tile[32][33];
  int bx = blockIdx.x % 144, by = blockIdx.x / 144;
  int n0 = bx * 32, k0 = by * 32;
  int tx = threadIdx.x & 31, ty = threadIdx.x >> 5;
  #pragma unroll
  for (int i = 0; i < 4; i++) {
    int k = k0 + ty + i * 8, n = n0 + tx;
    float v;
    if (n < 4096) v = wm[(size_t)k * 4096 + n];
    else {
      int nn = n - 4096, g = nn >> 7, j = nn & 127;
      const float* w = (g == 0) ? wix : (g == 1) ? wgx : (g == 2) ? wfx : wox;
      v = w[k * 128 + j];
    }
    tile[ty + i * 8][tx] = v;
  }
  __syncthreads();
  #pragma unroll
  for (int i = 0; i < 4; i++)
    dst[(size_t)(n0 + ty + i * 8) * 512 + k0 + tx] = f2bf(tile[tx][ty + i * 8]);
}

// transpose Wm[512:] -> bf16 [n=4096][k=1024]
__global__ __launch_bounds__(256) void k_twmh(
    const float* __restrict__ wm, unsigned short* __restrict__ dst)
{
  __shared__ float tile[32][33];
  int bx = blockIdx.x % 128, by = blockIdx.x / 128;
  int n0 = bx * 32, k0 = by * 32;
  int tx = threadIdx.x & 31, ty = threadIdx.x >> 5;
  #pragma unroll
  for (int i = 0; i < 4; i++)
    tile[ty + i * 8][tx] = wm[(size_t)(512 + k0 + ty + i * 8) * 4096 + n0 + tx];
  __syncthreads();
  #pragma unroll
  for (int i = 0; i < 4; i++)
    dst[(size_t)(n0 + ty + i * 8) * 1024 + k0 + tx] = f2bf(tile[tx][ty + i * 8]);
}

// ---------------------------------------------------------------------------
// Precompute GEMM: M=16384 K=512 N=4608, bf16 MFMA, 128x128 tile, 4 waves.
// n<4096 stored block-major: n' = (jh>>4)*64 + g*16 + (jh&15)
// ---------------------------------------------------------------------------
__global__ __launch_bounds__(256) void k_gemm(
    const float* __restrict__ x, const unsigned short* __restrict__ wt,
    unsigned short* __restrict__ preall)
{
  __shared__ unsigned short la[4096];
  __shared__ unsigned short lb[4096];
  int bid = blockIdx.x;
  int mb = bid % 128, nb = bid / 128;
  int m0 = mb * 128, n0 = nb * 128;
  int tid = threadIdx.x;
  int lane = tid & 63, wid = tid >> 6;
  int wr = (wid >> 1) * 64, wc = (wid & 1) * 64;
  f4 acc[4][4] = {};
  for (int kt = 0; kt < 16; kt++) {
    int k0 = kt * 32;
    __syncthreads();
    {
      int r = tid >> 1, kh = (tid & 1) * 16;
      const float4* srcA = (const float4*)(x + (size_t)(m0 + r) * 512 + k0 + kh);
      unsigned pk[8];
      #pragma unroll
      for (int q = 0; q < 4; q++) {
        float4 f = srcA[q];
        pk[q * 2]     = (unsigned)f2bf(f.x) | ((unsigned)f2bf(f.y) << 16);
        pk[q * 2 + 1] = (unsigned)f2bf(f.z) | ((unsigned)f2bf(f.w) << 16);
      }
      int base = r * 64 + kh * 2;
      u4 v0 = {pk[0], pk[1], pk[2], pk[3]}, v1 = {pk[4], pk[5], pk[6], pk[7]};
      *(u4*)((char*)la + ((base)      ^ ((r & 7) << 4))) = v0;
      *(u4*)((char*)la + ((base + 16) ^ ((r & 7) << 4))) = v1;
    }
    {
      int r = tid >> 1, kh = (tid & 1) * 16;
      const u4* srcB = (const u4*)(wt + (size_t)(n0 + r) * 512 + k0 + kh);
      u4 v0 = srcB[0], v1 = srcB[1];
      int base = r * 64 + kh * 2;
      *(u4*)((char*)lb + ((base)      ^ ((r & 7) << 4))) = v0;
      *(u4*)((char*)lb + ((base + 16) ^ ((r & 7) << 4))) = v1;
    }
    __syncthreads();
    int fo = (lane >> 4) * 16;
    sh8 af[4], bfr[4];
    #pragma unroll
    for (int mt = 0; mt < 4; mt++) {
      int r = wr + mt * 16 + (lane & 15);
      af[mt] = *(sh8*)((char*)la + ((r * 64 + fo) ^ ((r & 7) << 4)));
    }
    #pragma unroll
    for (int nt = 0; nt < 4; nt++) {
      int r = wc + nt * 16 + (lane & 15);
      bfr[nt] = *(sh8*)((char*)lb + ((r * 64 + fo) ^ ((r & 7) << 4)));
    }
    #pragma unroll
    for (int mt = 0; mt < 4; mt++)
      #pragma unroll
      for (int nt = 0; nt < 4; nt++)
        acc[mt][nt] = __builtin_amdgcn_mfma_f32_16x16x32_bf16(af[mt], bfr[nt], acc[mt][nt], 0, 0, 0);
  }
  #pragma unroll
  for (int mt = 0; mt < 4; mt++)
    #pragma unroll
    for (int nt = 0; nt < 4; nt++) {
      f4 a = acc[mt][nt];
      #pragma unroll
      for (int rr = 0; rr < 4; rr++) {
        int m = m0 + wr + mt * 16 + (lane >> 4) * 4 + rr;
        int n = n0 + wc + nt * 16 + (lane & 15);
        int b = m >> 9, t = m & 511;
        int nn;
        if (n < 4096) { int g = n >> 10, jh = n & 1023; nn = (jh >> 4) * 64 + g * 16 + (jh & 15); }
        else nn = n;
        preall[(size_t)(t * 32 + b) * NC4 + nn] = f2bf(a[rr]);
      }
    }
}

// ---------------------------------------------------------------------------
// Fused recurrence: 96 persistent blocks x 256 threads, R6 flag protocol with
// PACKED flags (4B stride: [0..63] h, [64..95] z) and single-dwordx4 poll.
//   blocks 0..63 : main LSTM, 16 h-cols each (R6 compute structure verbatim).
//   blocks 64..95: hyper LSTM, 1 batch row each (R6 verbatim).
// ---------------------------------------------------------------------------
__global__ __launch_bounds__(256, 1) void k_rec(
    const unsigned short* __restrict__ preall,
    const unsigned short* __restrict__ wmht,
    const unsigned short* __restrict__ whht,
    const float* __restrict__ pzt,
    float* __restrict__ zbuf,             // [512][32][48] fp32
    const float* __restrict__ pdx, const float* __restrict__ pdh,
    const float* __restrict__ pbw, const float* __restrict__ pbb,
    const float* __restrict__ bi, const float* __restrict__ bg,
    const float* __restrict__ bff, const float* __restrict__ bo,
    const float* __restrict__ lnig, const float* __restrict__ lnib,
    const float* __restrict__ lngg, const float* __restrict__ lngb,
    const float* __restrict__ lnfg, const float* __restrict__ lnfb,
    const float* __restrict__ lnog, const float* __restrict__ lnob,
    const float* __restrict__ lncg, const float* __restrict__ lncb,
    const float* __restrict__ pzxb, const float* __restrict__ pzhb,
    const float* __restrict__ pzbb,
    unsigned int* __restrict__ hbuf32,    // [2][32][512] u32 (bf16 pairs) ping-pong
    float* __restrict__ out,
    int* __restrict__ flags)              // [96] packed dwords
{
  __shared__ __align__(16) unsigned short wlds[64 * 1024];   // 128KB / hyper scratch
  __shared__ float red[2][32][68];
  __shared__ __align__(16) float zl[32 * 48];
  __shared__ float clds[512];
  __shared__ __align__(16) unsigned wxl[32][32];
  __shared__ float pdl[3][4][16];
  __shared__ float pbbl[16];

  const int tid = threadIdx.x;
  const int lane = tid & 63, wid = tid >> 6;

  if (blockIdx.x >= 64) {
    // =============== HYPER ROLE (b = blockIdx.x - 64) — R6 verbatim =======
    float* const hyp  = (float*)wlds;
    float* const pzl  = hyp;          // 48*132 floats
    float* const hhs  = hyp + 6400;   // 128
    float* const chs  = hyp + 6528;   // 128
    float* const actl = hyp + 6656;   // 4*128
    float* const rwav = hyp + 7168;   // 16
    float* const redc = hyp + 7184;   // 4

    const int b = blockIdx.x - 64;
    const int j = tid & 127, gp = tid >> 7;
    const int ga = gp, gb = gp + 2;

    u4 wa[16], wb[16];
    {
      const u4* s = (const u4*)(whht + (size_t)(ga * 128 + j) * 128);
      #pragma unroll
      for (int i = 0; i < 16; i++) wa[i] = s[i];
      const u4* s2 = (const u4*)(whht + (size_t)(gb * 128 + j) * 128);
      #pragma unroll
      for (int i = 0; i < 16; i++) wb[i] = s2[i];
    }
    for (int i = tid; i < 6144; i += 256)
      pzl[(i >> 7) * 132 + (i & 127)] = pzt[i];

    const float* bias_p[4] = {bi, bg, bff, bo};
    const float* lng_p[4]  = {lnig, lngg, lnfg, lnog};
    const float* lnb_p[4]  = {lnib, lngb, lnfb, lnob};
    float bias_a = bias_p[ga][j], bias_b = bias_p[gb][j];
    float lgam_a = lng_p[ga][j],  lbet_a = lnb_p[ga][j];
    float lgam_b = lng_p[gb][j],  lbet_b = lnb_p[gb][j];
    float lcg = 0.f, lcb = 0.f;
    if (tid < 128) { lcg = lncg[j]; lcb = lncb[j]; hhs[j] = 0.f; chs[j] = 0.f; }
    float zbias = 0.f;
    if (tid < 48) {
      int kind = tid >> 4, c = tid & 15;
      zbias = ((kind == 0) ? pzxb : (kind == 1) ? pzhb : pzbb)[c];
    }
    __syncthreads();

    const f4* h4 = (const f4*)hhs;
    for (int t = 0; t < NT; t++) {
      float xa = bf2f(preall[(size_t)(t * 32 + b) * NC4 + 4096 + ga * 128 + j]);
      float xb = bf2f(preall[(size_t)(t * 32 + b) * NC4 + 4096 + gb * 128 + j]);
      float sa = bias_a, sb = bias_b;
      #pragma unroll
      for (int i = 0; i < 16; i++) {
        f4 h0 = h4[2 * i], h1 = h4[2 * i + 1];
        u4 w = wa[i];
        sa += blo(w.x) * h0[0] + bhi(w.x) * h0[1] + blo(w.y) * h0[2] + bhi(w.y) * h0[3]
            + blo(w.z) * h1[0] + bhi(w.z) * h1[1] + blo(w.w) * h1[2] + bhi(w.w) * h1[3];
        w = wb[i];
        sb += blo(w.x) * h0[0] + bhi(w.x) * h0[1] + blo(w.y) * h0[2] + bhi(w.y) * h0[3]
            + blo(w.z) * h1[0] + bhi(w.z) * h1[1] + blo(w.w) * h1[2] + bhi(w.w) * h1[3];
      }
      sa += xa; sb += xb;
      float a1 = sa, a2 = sa * sa, b1 = sb, b2 = sb * sb;
      #pragma unroll
      for (int m = 1; m < 64; m <<= 1) {
        a1 += __shfl_xor(a1, m); a2 += __shfl_xor(a2, m);
        b1 += __shfl_xor(b1, m); b2 += __shfl_xor(b2, m);
      }
      if ((tid & 63) == 0) {
        int w = tid >> 6;
        rwav[w * 4] = a1; rwav[w * 4 + 1] = a2; rwav[w * 4 + 2] = b1; rwav[w * 4 + 3] = b2;
      }
      __syncthreads();
      int w0 = gp * 2, w1 = gp * 2 + 1;
      float sum_a = rwav[w0 * 4] + rwav[w1 * 4],         sq_a = rwav[w0 * 4 + 1] + rwav[w1 * 4 + 1];
      float sum_b = rwav[w0 * 4 + 2] + rwav[w1 * 4 + 2], sq_b = rwav[w0 * 4 + 3] + rwav[w1 * 4 + 3];
      float mean_a = sum_a * 0.0078125f, var_a = sq_a * 0.0078125f - mean_a * mean_a;
      float mean_b = sum_b * 0.0078125f, var_b = sq_b * 0.0078125f - mean_b * mean_b;
      float xn_a = (sa - mean_a) * rsqrtf(var_a + 1e-5f) * lgam_a + lbet_a;
      float xn_b = (sb - mean_b) * rsqrtf(var_b + 1e-5f) * lgam_b + lbet_b;
      float act_a = (ga == 1) ? tanhf(xn_a) : 1.f / (1.f + __expf(-xn_a));
      float act_b = 1.f / (1.f + __expf(-xn_b));
      actl[ga * 128 + j] = act_a;
      actl[gb * 128 + j] = act_b;
      __syncthreads();
      if (tid < 128) {
        float cn = actl[2 * 128 + j] * chs[j] + actl[j] * actl[128 + j];
        chs[j] = cn;
        float c1 = cn, c2 = cn * cn;
        #pragma unroll
        for (int m = 1; m < 64; m <<= 1) { c1 += __shfl_xor(c1, m); c2 += __shfl_xor(c2, m); }
        if ((tid & 63) == 0) { int w = tid >> 6; redc[w * 2] = c1; redc[w * 2 + 1] = c2; }
      }
      __syncthreads();
      if (tid < 128) {
        float sum2 = redc[0] + redc[2], sq2 = redc[1] + redc[3];
        float mean2 = sum2 * 0.0078125f, var2 = sq2 * 0.0078125f - mean2 * mean2;
        hhs[j] = actl[3 * 128 + j] * tanhf((chs[j] - mean2) * rsqrtf(var2 + 1e-5f) * lcg + lcb);
      }
      __syncthreads();
      if (tid < 48) {   // z = hh_new @ pz*_w + pz*_b -> publish via MALL store
        const f4* pr = (const f4*)(pzl + tid * 132);
        float zv = zbias;
        #pragma unroll 8
        for (int q = 0; q < 32; q++) {
          f4 p = pr[q], hv = h4[q];
          zv += p[0] * hv[0] + p[1] * hv[1] + p[2] * hv[2] + p[3] * hv[3];
        }
        union { float f; unsigned u; } cv; cv.f = zv;
        __hip_atomic_store((unsigned*)zbuf + (size_t)(t * 32 + b) * 48 + tid, cv.u,
                           __ATOMIC_RELAXED, __HIP_MEMORY_SCOPE_AGENT);
      }
      asm volatile("s_waitcnt vmcnt(0)" ::: "memory");
      __syncthreads();   // z stores drained block-wide; protects hhs/actl reuse
      if (tid == 0)
        __hip_atomic_store(flags + 64 + b, t + 1, __ATOMIC_RELAXED,
                           __HIP_MEMORY_SCOPE_AGENT);
    }
    return;
  }

  // ================= MAIN ROLE (blockIdx.x < 64) ==========================
  const int jh0 = blockIdx.x * 16;
  const int jw0 = blockIdx.x * 8;              // u32 col offset in hbuf32

  {   // stage weight slice once: n = g*16+jo -> wmht row g*NH + jh0 + jo
    int n = tid >> 2, kc = (tid & 3) * 256;
    int g = n >> 4, jo = n & 15;
    const unsigned short* src = wmht + (size_t)(g * NH + jh0 + jo) * NH + kc;
    #pragma unroll
    for (int i = 0; i < 32; i++) {
      sh8 v = *(const sh8*)(src + i * 8);
      int byte = n * 2048 + (kc + i * 8) * 2;
      *(sh8*)((char*)wlds + (byte ^ ((n & 7) << 4))) = v;
    }
  }
  clds[tid] = 0.f; clds[tid + 256] = 0.f;
  if (tid < 192) {
    int kind = tid >> 6, e = (tid >> 4) & 3, jo = tid & 15;
    const float* p = (kind == 0) ? pdx : (kind == 1) ? pdh : pbw;
    pdl[kind][e][jo] = p[e * NH + jh0 + jo];
  }
  if (tid < 16) pbbl[tid] = pbb[jh0 + tid];
  __syncthreads();

  const int bq = tid >> 3;       // combine row b: 0..31
  const int joB = (tid & 7) * 2; // combine adjacent col pair
  const int kh = wid >> 1, nh = wid & 1;
  const int col = lane & 15;

  // poll bases: lanes 0-15 cover h flags [lane*4..+3]; lanes 16-23 cover z
  const int zlane = (lane >= 16 && lane < 24) ? (lane - 16) : 0;
  const int* fbh = flags + lane * 4;          // valid for lane<16
  const int* fbz = flags + 64 + zlane * 4;

  for (int t = 0; t < NT; t++) {
    // ---- prefetch Wx into regs then stage (cached, block-major preall) ---
    {
      const u4* s = (const u4*)(preall + (size_t)(t * 32 + bq) * NC4
                                + (size_t)blockIdx.x * 64 + (tid & 7) * 8);
      *(u4*)&wxl[bq][(tid & 7) * 4] = *s;
    }
    // ---- wait for h(t) and z(t): wave0, packed dwordx4 poll, no sleep ----
    if (wid == 0) {
      for (;;) {
        u4 f, g;
        if (lane < 16)      LD16(f, fbh, "0");
        else if (lane < 24) LD16(g, fbz, "0");
        asm volatile("s_waitcnt vmcnt(0)" ::: "memory");
        int ok;
        if (lane < 16)
          ok = ((int)f.x >= t) & ((int)f.y >= t) & ((int)f.z >= t) & ((int)f.w >= t);
        else if (lane < 24)
          ok = ((int)g.x > t) & ((int)g.y > t) & ((int)g.z > t) & ((int)g.w > t);
        else ok = 1;
        if (__all(ok)) break;
      }
    }
    __syncthreads();
    asm volatile("" ::: "memory");
    if (tid < 192) {   // stage z(t) into LDS (data guaranteed by zflag)
      const f4* zs = (const f4*)(zbuf + (size_t)t * NB * 48) + tid * 2;
      f4 a = zs[0], bz = zs[1];
      f4* zd = (f4*)zl + tid * 2;
      zd[0] = a; zd[1] = bz;
    }
    const unsigned int* hc32 = hbuf32 + (t & 1) * (NB * NH / 2);
    // ---- W_h: wave = (kh, nh). A rows col & col+16, K-half kh. -----------
    {
      const unsigned int* bp0 = hc32 + col * 512 + kh * 256 + (lane >> 4) * 4;
      const unsigned int* bp1 = bp0 + 16 * 512;
      u4 a0r[16], a1r[16];
      #define LD2(i, OFFSTR) LD16(a0r[i], bp0, OFFSTR); LD16(a1r[i], bp1, OFFSTR)
      LD2(0, "0");    LD2(1, "64");   LD2(2, "128");  LD2(3, "192");
      LD2(4, "256");  LD2(5, "320");  LD2(6, "384");  LD2(7, "448");
      LD2(8, "512");  LD2(9, "576");  LD2(10, "640"); LD2(11, "704");
      LD2(12, "768"); LD2(13, "832"); LD2(14, "896"); LD2(15, "960");
      #undef LD2
      asm volatile("s_waitcnt vmcnt(0)" ::: "memory");
      __builtin_amdgcn_sched_barrier(0);
      f4 acc00 = {0,0,0,0}, acc01 = {0,0,0,0}, acc10 = {0,0,0,0}, acc11 = {0,0,0,0};
      const int koff = (lane >> 4) * 8;
      #pragma unroll
      for (int ks = 0; ks < 16; ks++) {
        int kb = kh * 512 + ks * 32 + koff;
        int n0 = nh * 32 + col, n1 = nh * 32 + 16 + col;
        sh8 b0 = *(sh8*)((char*)wlds + ((n0 * 2048 + kb * 2) ^ ((n0 & 7) << 4)));
        sh8 b1 = *(sh8*)((char*)wlds + ((n1 * 2048 + kb * 2) ^ ((n1 & 7) << 4)));
        union { u4 u; sh8 s; } A0, A1;
        A0.u = a0r[ks]; A1.u = a1r[ks];
        acc00 = __builtin_amdgcn_mfma_f32_16x16x32_bf16(A0.s, b0, acc00, 0, 0, 0);
        acc01 = __builtin_amdgcn_mfma_f32_16x16x32_bf16(A0.s, b1, acc01, 0, 0, 0);
        acc10 = __builtin_amdgcn_mfma_f32_16x16x32_bf16(A1.s, b0, acc10, 0, 0, 0);
        acc11 = __builtin_amdgcn_mfma_f32_16x16x32_bf16(A1.s, b1, acc11, 0, 0, 0);
      }
      int r0 = (lane >> 4) * 4;
      #pragma unroll
      for (int rr = 0; rr < 4; rr++) {
        red[kh][r0 + rr][nh * 32 + col]           = acc00[rr];
        red[kh][r0 + rr][nh * 32 + 16 + col]      = acc01[rr];
        red[kh][16 + r0 + rr][nh * 32 + col]      = acc10[rr];
        red[kh][16 + r0 + rr][nh * 32 + 16 + col] = acc11[rr];
      }
    }
    __syncthreads();
    // ---- combine: thread (bq, joB) handles adjacent jo = joB, joB+1 ------
    float hn2[2], cn2[2];
    {
      const float* zb_ = zl + bq * 48;
      const unsigned short* wxp = (const unsigned short*)&wxl[bq][0];
      #pragma unroll
      for (int half = 0; half < 2; half++) {
        int jo = joB + half;
        float gv[4];
        #pragma unroll
        for (int g = 0; g < 4; g++) {
          float wh = red[0][bq][g * 16 + jo] + red[1][bq][g * 16 + jo];
          float dxv = 0.f, dhv = 0.f, bdv = pbbl[jo];
          #pragma unroll
          for (int e = 0; e < 4; e++) {
            dxv += zb_[g * 4 + e]      * pdl[0][e][jo];
            dhv += zb_[16 + g * 4 + e] * pdl[1][e][jo];
            bdv += zb_[32 + g * 4 + e] * pdl[2][e][jo];
          }
          float wxv = bf2f(wxp[g * 16 + jo]);
          gv[g] = wxv * dxv + wh * dhv + bdv;
        }
        float iv = 1.f / (1.f + __expf(-gv[0]));
        float fv = 1.f / (1.f + __expf(-gv[1]));
        float ov = 1.f / (1.f + __expf(-gv[2]));
        float gg = tanhf(gv[3]);
        int ci = bq * 16 + jo;
        float cn = fv * clds[ci] + iv * gg;
        clds[ci] = cn;
        hn2[half] = ov * tanhf(cn);
        cn2[half] = cn;
      }
      // publish h(t+1) FIRST (only store before the drain)
      unsigned val = (unsigned)f2bf(hn2[0]) | ((unsigned)f2bf(hn2[1]) << 16);
      __hip_atomic_store(hbuf32 + ((t + 1) & 1) * (NB * NH / 2) + bq * 512 + jw0 + (joB >> 1),
                         val, __ATOMIC_RELAXED, __HIP_MEMORY_SCOPE_AGENT);
    }
    // ---- drain h stores only, barrier, flag; out[] writes AFTER flag -----
    asm volatile("s_waitcnt vmcnt(0)" ::: "memory");
    __syncthreads();   // all waves' h stores drained; protects red/zl/wxl/clds
    if (tid == 0)
      __hip_atomic_store(flags + blockIdx.x, t + 1, __ATOMIC_RELAXED,
                         __HIP_MEMORY_SCOPE_AGENT);
    *(float2*)&out[(size_t)(bq * NT + t) * NH + jh0 + joB] = make_float2(hn2[0], hn2[1]);
    if (t == NT - 1) {
      *(float2*)&out[(size_t)NB * NT * NH + bq * NH + jh0 + joB] = make_float2(hn2[0], hn2[1]);
      *(float2*)&out[(size_t)NB * NT * NH + NB * NH + bq * NH + jh0 + joB] = make_float2(cn2[0], cn2[1]);
    }
  }
}

// ---------------------------------------------------------------------------
extern "C" void kernel_launch(void* const* d_in, const int* in_sizes, int n_in,
                              void* d_out, int out_size, void* d_ws, size_t ws_size,
                              hipStream_t stream) {
  (void)in_sizes; (void)n_in; (void)out_size;
  const float* x    = (const float*)d_in[0];
  const float* Wm   = (const float*)d_in[1];
  const float* Wih  = (const float*)d_in[2];
  const float* Wix  = (const float*)d_in[3];
  const float* bi   = (const float*)d_in[4];
  const float* Wgh  = (const float*)d_in[5];
  const float* Wgx  = (const float*)d_in[6];
  const float* bg   = (const float*)d_in[7];
  const float* Wfh  = (const float*)d_in[8];
  const float* Wfx  = (const float*)d_in[9];
  const float* bfp  = (const float*)d_in[10];
  const float* Woh  = (const float*)d_in[11];
  const float* Wox  = (const float*)d_in[12];
  const float* bo   = (const float*)d_in[13];
  const float* lnig = (const float*)d_in[14];
  const float* lnib = (const float*)d_in[15];
  const float* lngg = (const float*)d_in[16];
  const float* lngb = (const float*)d_in[17];
  const float* lnfg = (const float*)d_in[18];
  const float* lnfb = (const float*)d_in[19];
  const float* lnog = (const float*)d_in[20];
  const float* lnob = (const float*)d_in[21];
  const float* lncg = (const float*)d_in[22];
  const float* lncb = (const float*)d_in[23];
  const float* pzxw = (const float*)d_in[24];
  const float* pzxb = (const float*)d_in[25];
  const float* pzhw = (const float*)d_in[26];
  const float* pzhb = (const float*)d_in[27];
  const float* pzbw = (const float*)d_in[28];
  const float* pzbb = (const float*)d_in[29];
  const float* pdx  = (const float*)d_in[30];
  const float* pdh  = (const float*)d_in[31];
  const float* pbw  = (const float*)d_in[32];
  const float* pbb  = (const float*)d_in[33];
  float* out = (float*)d_out;

  char* ws = (char*)d_ws;
  size_t off = 0;
  auto alloc = [&](size_t bytes) {
    char* p = ws + off; off += (bytes + 255) & ~(size_t)255; return p;
  };
  unsigned short* preall = (unsigned short*)alloc((size_t)16384 * NC4 * 2);
  unsigned short* wcat   = (unsigned short*)alloc((size_t)NC4 * 512 * 2);
  unsigned short* wmht   = (unsigned short*)alloc((size_t)4096 * 1024 * 2);
  unsigned short* whht   = (unsigned short*)alloc((size_t)4 * 128 * 128 * 2);
  float* pzt             = (float*)alloc((size_t)3 * 16 * 128 * 4);
  float* zbuf            = (float*)alloc((size_t)NT * NB * 48 * 4);
  unsigned int* hbuf32   = (unsigned int*)alloc((size_t)2 * NB * NH * 2);
  int* flags             = (int*)alloc((size_t)96 * 4);
  if (off > ws_size) return;  // ws too small: leave output untouched (diagnosable)

  k_prep<<<256, 256, 0, stream>>>(Wih, Wgh, Wfh, Woh, pzxw, pzhw, pzbw, whht, pzt, hbuf32, flags);
  k_twcat<<<2304, 256, 0, stream>>>(Wm, Wix, Wgx, Wfx, Wox, wcat);
  k_twmh<<<4096, 256, 0, stream>>>(Wm, wmht);
  k_gemm<<<4608, 256, 0, stream>>>(x, wcat, preall);
  k_rec<<<96, 256, 0, stream>>>(preall, wmht, whht, pzt, zbuf,
      pdx, pdh, pbw, pbb, bi, bg, bfp, bo,
      lnig, lnib, lngg, lngb, lnfg, lnfb, lnog, lnob, lncg, lncb,
      pzxb, pzhb, pzbb, hbuf32, out, flags);
}

// Round 12
// 3324.857 us; speedup vs baseline: 1.4879x; 1.2183x over previous
//
#include <hip/hip_runtime.h>
#include <cstdint>
#include <cstddef>

#define NB 32       // batch
#define NT 512      // time steps
#define ND 512      // input dim D
#define NH 1024     // hidden H
#define NC4 4608    // 4H + 4*HH (fused GEMM N)

typedef short sh8 __attribute__((ext_vector_type(8)));   // 8 bf16 (raw bits)
typedef float f4  __attribute__((ext_vector_type(4)));
typedef unsigned int u4 __attribute__((ext_vector_type(4)));

__device__ __forceinline__ unsigned short f2bf(float x) {
  union { float f; unsigned u; } v; v.f = x;
  unsigned r = v.u + 0x7FFFu + ((v.u >> 16) & 1u);   // RNE
  return (unsigned short)(r >> 16);
}
__device__ __forceinline__ float bf2f(unsigned short b) {
  union { unsigned u; float f; } v; v.u = ((unsigned)b) << 16; return v.f;
}
__device__ __forceinline__ float blo(unsigned w) { union { unsigned u; float f; } v; v.u = w << 16; return v.f; }
__device__ __forceinline__ float bhi(unsigned w) { union { unsigned u; float f; } v; v.u = w & 0xFFFF0000u; return v.f; }

// MALL-coherent 16B load: bypasses L1/L2 (sc0 sc1).
#define LD16(dst, base, OFFSTR)                                         \
  asm volatile("global_load_dwordx4 %0, %1, off offset:" OFFSTR " sc0 sc1" \
               : "=v"(dst) : "v"(base))

// ---------------------------------------------------------------------------
// prep: hyper gate weights -> bf16 transposed; pz weights -> fp32 transposed;
//       zero h buf0; zero 96 packed flags
// ---------------------------------------------------------------------------
__global__ __launch_bounds__(256) void k_prep(
    const float* __restrict__ wih, const float* __restrict__ wgh,
    const float* __restrict__ wfh, const float* __restrict__ woh,
    const float* __restrict__ pzx, const float* __restrict__ pzh,
    const float* __restrict__ pzb,
    unsigned short* __restrict__ whht, float* __restrict__ pzt,
    unsigned int* __restrict__ hbuf32, int* __restrict__ flags)
{
  int idx = blockIdx.x * 256 + threadIdx.x;
  if (idx < 65536) {  // 4*128*128
    int g = idx >> 14, r = idx & 16383, j = r >> 7, k = r & 127;
    const float* w = (g == 0) ? wih : (g == 1) ? wgh : (g == 2) ? wfh : woh;
    whht[idx] = f2bf(w[k * 128 + j]);
  }
  if (idx < 6144) {   // 3*16*128
    int r = idx & 2047, c = r >> 7, k = r & 127;
    int kind = idx >> 11;
    const float* p = (kind == 0) ? pzx : (kind == 1) ? pzh : pzb;
    pzt[idx] = p[k * 16 + c];
    (void)c; (void)k;
  }
  if (idx < 16384)   // zero buf0 (32*1024 bf16) via MALL so bypass-reads see it
    __hip_atomic_store(hbuf32 + idx, 0u, __ATOMIC_RELAXED, __HIP_MEMORY_SCOPE_AGENT);
  if (idx < 96)      // packed flags: [0..63] h, [64..95] z
    __hip_atomic_store(flags + idx, 0, __ATOMIC_RELAXED, __HIP_MEMORY_SCOPE_AGENT);
}

// ---------------------------------------------------------------------------
// transpose Wcat -> bf16 [n=4608][k=512]: n<4096 from Wm[:512], else Wi/g/f/o_x
// ---------------------------------------------------------------------------
__global__ __launch_bounds__(256) void k_twcat(
    const float* __restrict__ wm, const float* __restrict__ wix,
    const float* __restrict__ wgx, const float* __restrict__ wfx,
    const float* __restrict__ wox, unsigned short* __restrict__ dst)
{
  __shared__ float tile[32][33];
  int bx = blockIdx.x % 144, by = blockIdx.x / 144;
  int n0 = bx * 32, k0 = by * 32;
  int tx = threadIdx.x & 31, ty = threadIdx.x >> 5;
  #pragma unroll
  for (int i = 0; i < 4; i++) {
    int k = k0 + ty + i * 8, n = n0 + tx;
    float v;
    if (n < 4096) v = wm[(size_t)k * 4096 + n];
    else {
      int nn = n - 4096, g = nn >> 7, j = nn & 127;
      const float* w = (g == 0) ? wix : (g == 1) ? wgx : (g == 2) ? wfx : wox;
      v = w[k * 128 + j];
    }
    tile[ty + i * 8][tx] = v;
  }
  __syncthreads();
  #pragma unroll
  for (int i = 0; i < 4; i++)
    dst[(size_t)(n0 + ty + i * 8) * 512 + k0 + tx] = f2bf(tile[tx][ty + i * 8]);
}

// transpose Wm[512:] -> bf16 [n=4096][k=1024]
__global__ __launch_bounds__(256) void k_twmh(
    const float* __restrict__ wm, unsigned short* __restrict__ dst)
{
  __shared__ float tile[32][33];
  int bx = blockIdx.x % 128, by = blockIdx.x / 128;
  int n0 = bx * 32, k0 = by * 32;
  int tx = threadIdx.x & 31, ty = threadIdx.x >> 5;
  #pragma unroll
  for (int i = 0; i < 4; i++)
    tile[ty + i * 8][tx] = wm[(size_t)(512 + k0 + ty + i * 8) * 4096 + n0 + tx];
  __syncthreads();
  #pragma unroll
  for (int i = 0; i < 4; i++)
    dst[(size_t)(n0 + ty + i * 8) * 1024 + k0 + tx] = f2bf(tile[tx][ty + i * 8]);
}

// ---------------------------------------------------------------------------
// Precompute GEMM: M=16384 K=512 N=4608, bf16 MFMA, 128x128 tile, 4 waves.
// n<4096 stored block-major: n' = (jh>>4)*64 + g*16 + (jh&15)
// ---------------------------------------------------------------------------
__global__ __launch_bounds__(256) void k_gemm(
    const float* __restrict__ x, const unsigned short* __restrict__ wt,
    unsigned short* __restrict__ preall)
{
  __shared__ unsigned short la[4096];
  __shared__ unsigned short lb[4096];
  int bid = blockIdx.x;
  int mb = bid % 128, nb = bid / 128;
  int m0 = mb * 128, n0 = nb * 128;
  int tid = threadIdx.x;
  int lane = tid & 63, wid = tid >> 6;
  int wr = (wid >> 1) * 64, wc = (wid & 1) * 64;
  f4 acc[4][4] = {};
  for (int kt = 0; kt < 16; kt++) {
    int k0 = kt * 32;
    __syncthreads();
    {
      int r = tid >> 1, kh = (tid & 1) * 16;
      const float4* srcA = (const float4*)(x + (size_t)(m0 + r) * 512 + k0 + kh);
      unsigned pk[8];
      #pragma unroll
      for (int q = 0; q < 4; q++) {
        float4 f = srcA[q];
        pk[q * 2]     = (unsigned)f2bf(f.x) | ((unsigned)f2bf(f.y) << 16);
        pk[q * 2 + 1] = (unsigned)f2bf(f.z) | ((unsigned)f2bf(f.w) << 16);
      }
      int base = r * 64 + kh * 2;
      u4 v0 = {pk[0], pk[1], pk[2], pk[3]}, v1 = {pk[4], pk[5], pk[6], pk[7]};
      *(u4*)((char*)la + ((base)      ^ ((r & 7) << 4))) = v0;
      *(u4*)((char*)la + ((base + 16) ^ ((r & 7) << 4))) = v1;
    }
    {
      int r = tid >> 1, kh = (tid & 1) * 16;
      const u4* srcB = (const u4*)(wt + (size_t)(n0 + r) * 512 + k0 + kh);
      u4 v0 = srcB[0], v1 = srcB[1];
      int base = r * 64 + kh * 2;
      *(u4*)((char*)lb + ((base)      ^ ((r & 7) << 4))) = v0;
      *(u4*)((char*)lb + ((base + 16) ^ ((r & 7) << 4))) = v1;
    }
    __syncthreads();
    int fo = (lane >> 4) * 16;
    sh8 af[4], bfr[4];
    #pragma unroll
    for (int mt = 0; mt < 4; mt++) {
      int r = wr + mt * 16 + (lane & 15);
      af[mt] = *(sh8*)((char*)la + ((r * 64 + fo) ^ ((r & 7) << 4)));
    }
    #pragma unroll
    for (int nt = 0; nt < 4; nt++) {
      int r = wc + nt * 16 + (lane & 15);
      bfr[nt] = *(sh8*)((char*)lb + ((r * 64 + fo) ^ ((r & 7) << 4)));
    }
    #pragma unroll
    for (int mt = 0; mt < 4; mt++)
      #pragma unroll
      for (int nt = 0; nt < 4; nt++)
        acc[mt][nt] = __builtin_amdgcn_mfma_f32_16x16x32_bf16(af[mt], bfr[nt], acc[mt][nt], 0, 0, 0);
  }
  #pragma unroll
  for (int mt = 0; mt < 4; mt++)
    #pragma unroll
    for (int nt = 0; nt < 4; nt++) {
      f4 a = acc[mt][nt];
      #pragma unroll
      for (int rr = 0; rr < 4; rr++) {
        int m = m0 + wr + mt * 16 + (lane >> 4) * 4 + rr;
        int n = n0 + wc + nt * 16 + (lane & 15);
        int b = m >> 9, t = m & 511;
        int nn;
        if (n < 4096) { int g = n >> 10, jh = n & 1023; nn = (jh >> 4) * 64 + g * 16 + (jh & 15); }
        else nn = n;
        preall[(size_t)(t * 32 + b) * NC4 + nn] = f2bf(a[rr]);
      }
    }
}

// ---------------------------------------------------------------------------
// Fused recurrence: 96 persistent blocks x 256 threads, R6 flag protocol,
// packed flags, duplication-free h loads: wave = (kh = K-half, rh = row-half),
// each wave loads 16 rows x K-half (16 LD16/lane) -> 64KB/block/step (1x).
//   blocks 0..63 : main LSTM, 16 h-cols each.
//   blocks 64..95: hyper LSTM, 1 batch row each (R6 verbatim).
// ---------------------------------------------------------------------------
__global__ __launch_bounds__(256, 1) void k_rec(
    const unsigned short* __restrict__ preall,
    const unsigned short* __restrict__ wmht,
    const unsigned short* __restrict__ whht,
    const float* __restrict__ pzt,
    float* __restrict__ zbuf,             // [512][32][48] fp32
    const float* __restrict__ pdx, const float* __restrict__ pdh,
    const float* __restrict__ pbw, const float* __restrict__ pbb,
    const float* __restrict__ bi, const float* __restrict__ bg,
    const float* __restrict__ bff, const float* __restrict__ bo,
    const float* __restrict__ lnig, const float* __restrict__ lnib,
    const float* __restrict__ lngg, const float* __restrict__ lngb,
    const float* __restrict__ lnfg, const float* __restrict__ lnfb,
    const float* __restrict__ lnog, const float* __restrict__ lnob,
    const float* __restrict__ lncg, const float* __restrict__ lncb,
    const float* __restrict__ pzxb, const float* __restrict__ pzhb,
    const float* __restrict__ pzbb,
    unsigned int* __restrict__ hbuf32,    // [2][32][512] u32 (bf16 pairs) ping-pong
    float* __restrict__ out,
    int* __restrict__ flags)              // [96] packed dwords
{
  __shared__ __align__(16) unsigned short wlds[64 * 1024];   // 128KB / hyper scratch
  __shared__ float red[2][32][68];
  __shared__ __align__(16) float zl[32 * 48];
  __shared__ float clds[512];
  __shared__ __align__(16) unsigned wxl[32][32];
  __shared__ float pdl[3][4][16];
  __shared__ float pbbl[16];

  const int tid = threadIdx.x;
  const int lane = tid & 63, wid = tid >> 6;

  if (blockIdx.x >= 64) {
    // =============== HYPER ROLE (b = blockIdx.x - 64) — R6 verbatim =======
    float* const hyp  = (float*)wlds;
    float* const pzl  = hyp;          // 48*132 floats
    float* const hhs  = hyp + 6400;   // 128
    float* const chs  = hyp + 6528;   // 128
    float* const actl = hyp + 6656;   // 4*128
    float* const rwav = hyp + 7168;   // 16
    float* const redc = hyp + 7184;   // 4

    const int b = blockIdx.x - 64;
    const int j = tid & 127, gp = tid >> 7;
    const int ga = gp, gb = gp + 2;

    u4 wa[16], wb[16];
    {
      const u4* s = (const u4*)(whht + (size_t)(ga * 128 + j) * 128);
      #pragma unroll
      for (int i = 0; i < 16; i++) wa[i] = s[i];
      const u4* s2 = (const u4*)(whht + (size_t)(gb * 128 + j) * 128);
      #pragma unroll
      for (int i = 0; i < 16; i++) wb[i] = s2[i];
    }
    for (int i = tid; i < 6144; i += 256)
      pzl[(i >> 7) * 132 + (i & 127)] = pzt[i];

    const float* bias_p[4] = {bi, bg, bff, bo};
    const float* lng_p[4]  = {lnig, lngg, lnfg, lnog};
    const float* lnb_p[4]  = {lnib, lngb, lnfb, lnob};
    float bias_a = bias_p[ga][j], bias_b = bias_p[gb][j];
    float lgam_a = lng_p[ga][j],  lbet_a = lnb_p[ga][j];
    float lgam_b = lng_p[gb][j],  lbet_b = lnb_p[gb][j];
    float lcg = 0.f, lcb = 0.f;
    if (tid < 128) { lcg = lncg[j]; lcb = lncb[j]; hhs[j] = 0.f; chs[j] = 0.f; }
    float zbias = 0.f;
    if (tid < 48) {
      int kind = tid >> 4, c = tid & 15;
      zbias = ((kind == 0) ? pzxb : (kind == 1) ? pzhb : pzbb)[c];
    }
    __syncthreads();

    const f4* h4 = (const f4*)hhs;
    for (int t = 0; t < NT; t++) {
      float xa = bf2f(preall[(size_t)(t * 32 + b) * NC4 + 4096 + ga * 128 + j]);
      float xb = bf2f(preall[(size_t)(t * 32 + b) * NC4 + 4096 + gb * 128 + j]);
      float sa = bias_a, sb = bias_b;
      #pragma unroll
      for (int i = 0; i < 16; i++) {
        f4 h0 = h4[2 * i], h1 = h4[2 * i + 1];
        u4 w = wa[i];
        sa += blo(w.x) * h0[0] + bhi(w.x) * h0[1] + blo(w.y) * h0[2] + bhi(w.y) * h0[3]
            + blo(w.z) * h1[0] + bhi(w.z) * h1[1] + blo(w.w) * h1[2] + bhi(w.w) * h1[3];
        w = wb[i];
        sb += blo(w.x) * h0[0] + bhi(w.x) * h0[1] + blo(w.y) * h0[2] + bhi(w.y) * h0[3]
            + blo(w.z) * h1[0] + bhi(w.z) * h1[1] + blo(w.w) * h1[2] + bhi(w.w) * h1[3];
      }
      sa += xa; sb += xb;
      float a1 = sa, a2 = sa * sa, b1 = sb, b2 = sb * sb;
      #pragma unroll
      for (int m = 1; m < 64; m <<= 1) {
        a1 += __shfl_xor(a1, m); a2 += __shfl_xor(a2, m);
        b1 += __shfl_xor(b1, m); b2 += __shfl_xor(b2, m);
      }
      if ((tid & 63) == 0) {
        int w = tid >> 6;
        rwav[w * 4] = a1; rwav[w * 4 + 1] = a2; rwav[w * 4 + 2] = b1; rwav[w * 4 + 3] = b2;
      }
      __syncthreads();
      int w0 = gp * 2, w1 = gp * 2 + 1;
      float sum_a = rwav[w0 * 4] + rwav[w1 * 4],         sq_a = rwav[w0 * 4 + 1] + rwav[w1 * 4 + 1];
      float sum_b = rwav[w0 * 4 + 2] + rwav[w1 * 4 + 2], sq_b = rwav[w0 * 4 + 3] + rwav[w1 * 4 + 3];
      float mean_a = sum_a * 0.0078125f, var_a = sq_a * 0.0078125f - mean_a * mean_a;
      float mean_b = sum_b * 0.0078125f, var_b = sq_b * 0.0078125f - mean_b * mean_b;
      float xn_a = (sa - mean_a) * rsqrtf(var_a + 1e-5f) * lgam_a + lbet_a;
      float xn_b = (sb - mean_b) * rsqrtf(var_b + 1e-5f) * lgam_b + lbet_b;
      float act_a = (ga == 1) ? tanhf(xn_a) : 1.f / (1.f + __expf(-xn_a));
      float act_b = 1.f / (1.f + __expf(-xn_b));
      actl[ga * 128 + j] = act_a;
      actl[gb * 128 + j] = act_b;
      __syncthreads();
      if (tid < 128) {
        float cn = actl[2 * 128 + j] * chs[j] + actl[j] * actl[128 + j];
        chs[j] = cn;
        float c1 = cn, c2 = cn * cn;
        #pragma unroll
        for (int m = 1; m < 64; m <<= 1) { c1 += __shfl_xor(c1, m); c2 += __shfl_xor(c2, m); }
        if ((tid & 63) == 0) { int w = tid >> 6; redc[w * 2] = c1; redc[w * 2 + 1] = c2; }
      }
      __syncthreads();
      if (tid < 128) {
        float sum2 = redc[0] + redc[2], sq2 = redc[1] + redc[3];
        float mean2 = sum2 * 0.0078125f, var2 = sq2 * 0.0078125f - mean2 * mean2;
        hhs[j] = actl[3 * 128 + j] * tanhf((chs[j] - mean2) * rsqrtf(var2 + 1e-5f) * lcg + lcb);
      }
      __syncthreads();
      if (tid < 48) {   // z = hh_new @ pz*_w + pz*_b -> publish via MALL store
        const f4* pr = (const f4*)(pzl + tid * 132);
        float zv = zbias;
        #pragma unroll 8
        for (int q = 0; q < 32; q++) {
          f4 p = pr[q], hv = h4[q];
          zv += p[0] * hv[0] + p[1] * hv[1] + p[2] * hv[2] + p[3] * hv[3];
        }
        union { float f; unsigned u; } cv; cv.f = zv;
        __hip_atomic_store((unsigned*)zbuf + (size_t)(t * 32 + b) * 48 + tid, cv.u,
                           __ATOMIC_RELAXED, __HIP_MEMORY_SCOPE_AGENT);
      }
      asm volatile("s_waitcnt vmcnt(0)" ::: "memory");
      __syncthreads();   // z stores drained block-wide; protects hhs/actl reuse
      if (tid == 0)
        __hip_atomic_store(flags + 64 + b, t + 1, __ATOMIC_RELAXED,
                           __HIP_MEMORY_SCOPE_AGENT);
    }
    return;
  }

  // ================= MAIN ROLE (blockIdx.x < 64) ==========================
  const int jh0 = blockIdx.x * 16;
  const int jw0 = blockIdx.x * 8;              // u32 col offset in hbuf32

  {   // stage weight slice once: n = g*16+jo -> wmht row g*NH + jh0 + jo
    int n = tid >> 2, kc = (tid & 3) * 256;
    int g = n >> 4, jo = n & 15;
    const unsigned short* src = wmht + (size_t)(g * NH + jh0 + jo) * NH + kc;
    #pragma unroll
    for (int i = 0; i < 32; i++) {
      sh8 v = *(const sh8*)(src + i * 8);
      int byte = n * 2048 + (kc + i * 8) * 2;
      *(sh8*)((char*)wlds + (byte ^ ((n & 7) << 4))) = v;
    }
  }
  clds[tid] = 0.f; clds[tid + 256] = 0.f;
  if (tid < 192) {
    int kind = tid >> 6, e = (tid >> 4) & 3, jo = tid & 15;
    const float* p = (kind == 0) ? pdx : (kind == 1) ? pdh : pbw;
    pdl[kind][e][jo] = p[e * NH + jh0 + jo];
  }
  if (tid < 16) pbbl[tid] = pbb[jh0 + tid];
  __syncthreads();

  const int bq = tid >> 3;       // combine row b: 0..31
  const int joB = (tid & 7) * 2; // combine adjacent col pair
  const int kh = wid >> 1;       // K-half
  const int rh = wid & 1;        // row-half
  const int col = lane & 15;
  const int grp = lane >> 4;     // 0..3
  const int row = rh * 16 + col; // the single b-row this lane loads

  // poll bases: lanes 0-15 cover h flags [lane*4..+3]; lanes 16-23 cover z
  const int zlane = (lane >= 16 && lane < 24) ? (lane - 16) : 0;
  const int* fbh = flags + lane * 4;          // valid for lane<16
  const int* fbz = flags + 64 + zlane * 4;

  for (int t = 0; t < NT; t++) {
    // ---- stage wx slab (cached, block-major preall) -----------------------
    {
      const u4* s = (const u4*)(preall + (size_t)(t * 32 + bq) * NC4
                                + (size_t)blockIdx.x * 64 + (tid & 7) * 8);
      *(u4*)&wxl[bq][(tid & 7) * 4] = *s;
    }
    // ---- wait for h(t) and z(t): wave0, packed dwordx4 poll ---------------
    if (wid == 0) {
      for (;;) {
        u4 f, g;
        if (lane < 16)      LD16(f, fbh, "0");
        else if (lane < 24) LD16(g, fbz, "0");
        asm volatile("s_waitcnt vmcnt(0)" ::: "memory");
        int ok;
        if (lane < 16)
          ok = ((int)f.x >= t) & ((int)f.y >= t) & ((int)f.z >= t) & ((int)f.w >= t);
        else if (lane < 24)
          ok = ((int)g.x > t) & ((int)g.y > t) & ((int)g.z > t) & ((int)g.w > t);
        else ok = 1;
        if (__all(ok)) break;
      }
    }
    __syncthreads();
    asm volatile("" ::: "memory");
    if (tid < 192) {   // stage z(t) into LDS (data guaranteed by zflag)
      const f4* zs = (const f4*)(zbuf + (size_t)t * NB * 48) + tid * 2;
      f4 a = zs[0], bz = zs[1];
      f4* zd = (f4*)zl + tid * 2;
      zd[0] = a; zd[1] = bz;
    }
    const unsigned int* hc32 = hbuf32 + (t & 1) * (NB * NH / 2);
    // ---- W_h: wave = (kh, rh): 16 rows x K-half, 16 LD16/lane, no dup ----
    {
      const unsigned int* bp = hc32 + row * 512 + kh * 256 + grp * 4;
      u4 ar[16];
      LD16(ar[0],  bp, "0");    LD16(ar[1],  bp, "64");
      LD16(ar[2],  bp, "128");  LD16(ar[3],  bp, "192");
      LD16(ar[4],  bp, "256");  LD16(ar[5],  bp, "320");
      LD16(ar[6],  bp, "384");  LD16(ar[7],  bp, "448");
      LD16(ar[8],  bp, "512");  LD16(ar[9],  bp, "576");
      LD16(ar[10], bp, "640");  LD16(ar[11], bp, "704");
      LD16(ar[12], bp, "768");  LD16(ar[13], bp, "832");
      LD16(ar[14], bp, "896");  LD16(ar[15], bp, "960");
      asm volatile("s_waitcnt vmcnt(0)" ::: "memory");
      __builtin_amdgcn_sched_barrier(0);
      f4 acc0 = {0,0,0,0}, acc1 = {0,0,0,0}, acc2 = {0,0,0,0}, acc3 = {0,0,0,0};
      #pragma unroll
      for (int ks = 0; ks < 16; ks++) {
        int kb = kh * 512 + ks * 32 + grp * 8;
        union { u4 u; sh8 s; } A; A.u = ar[ks];
        int n0 = col, n1 = 16 + col, n2 = 32 + col, n3 = 48 + col;
        sh8 b0 = *(sh8*)((char*)wlds + ((n0 * 2048 + kb * 2) ^ ((n0 & 7) << 4)));
        sh8 b1 = *(sh8*)((char*)wlds + ((n1 * 2048 + kb * 2) ^ ((n1 & 7) << 4)));
        sh8 b2 = *(sh8*)((char*)wlds + ((n2 * 2048 + kb * 2) ^ ((n2 & 7) << 4)));
        sh8 b3 = *(sh8*)((char*)wlds + ((n3 * 2048 + kb * 2) ^ ((n3 & 7) << 4)));
        acc0 = __builtin_amdgcn_mfma_f32_16x16x32_bf16(A.s, b0, acc0, 0, 0, 0);
        acc1 = __builtin_amdgcn_mfma_f32_16x16x32_bf16(A.s, b1, acc1, 0, 0, 0);
        acc2 = __builtin_amdgcn_mfma_f32_16x16x32_bf16(A.s, b2, acc2, 0, 0, 0);
        acc3 = __builtin_amdgcn_mfma_f32_16x16x32_bf16(A.s, b3, acc3, 0, 0, 0);
      }
      int r0 = rh * 16 + grp * 4;
      #pragma unroll
      for (int rr = 0; rr < 4; rr++) {
        red[kh][r0 + rr][col]      = acc0[rr];
        red[kh][r0 + rr][16 + col] = acc1[rr];
        red[kh][r0 + rr][32 + col] = acc2[rr];
        red[kh][r0 + rr][48 + col] = acc3[rr];
      }
    }
    __syncthreads();
    // ---- combine: thread (bq, joB) handles adjacent jo = joB, joB+1 ------
    float hn2[2], cn2[2];
    {
      const float* zb_ = zl + bq * 48;
      const unsigned short* wxp = (const unsigned short*)&wxl[bq][0];
      #pragma unroll
      for (int half = 0; half < 2; half++) {
        int jo = joB + half;
        float gv[4];
        #pragma unroll
        for (int g = 0; g < 4; g++) {
          float wh = red[0][bq][g * 16 + jo] + red[1][bq][g * 16 + jo];
          float dxv = 0.f, dhv = 0.f, bdv = pbbl[jo];
          #pragma unroll
          for (int e = 0; e < 4; e++) {
            dxv += zb_[g * 4 + e]      * pdl[0][e][jo];
            dhv += zb_[16 + g * 4 + e] * pdl[1][e][jo];
            bdv += zb_[32 + g * 4 + e] * pdl[2][e][jo];
          }
          float wxv = bf2f(wxp[g * 16 + jo]);
          gv[g] = wxv * dxv + wh * dhv + bdv;
        }
        float iv = 1.f / (1.f + __expf(-gv[0]));
        float fv = 1.f / (1.f + __expf(-gv[1]));
        float ov = 1.f / (1.f + __expf(-gv[2]));
        float gg = tanhf(gv[3]);
        int ci = bq * 16 + jo;
        float cn = fv * clds[ci] + iv * gg;
        clds[ci] = cn;
        hn2[half] = ov * tanhf(cn);
        cn2[half] = cn;
      }
      // publish h(t+1) FIRST (only store before the drain)
      unsigned val = (unsigned)f2bf(hn2[0]) | ((unsigned)f2bf(hn2[1]) << 16);
      __hip_atomic_store(hbuf32 + ((t + 1) & 1) * (NB * NH / 2) + bq * 512 + jw0 + (joB >> 1),
                         val, __ATOMIC_RELAXED, __HIP_MEMORY_SCOPE_AGENT);
    }
    // ---- drain h stores only, barrier, flag; out[] writes AFTER flag -----
    asm volatile("s_waitcnt vmcnt(0)" ::: "memory");
    __syncthreads();   // all waves' h stores drained; protects red/zl/wxl/clds
    if (tid == 0)
      __hip_atomic_store(flags + blockIdx.x, t + 1, __ATOMIC_RELAXED,
                         __HIP_MEMORY_SCOPE_AGENT);
    *(float2*)&out[(size_t)(bq * NT + t) * NH + jh0 + joB] = make_float2(hn2[0], hn2[1]);
    if (t == NT - 1) {
      *(float2*)&out[(size_t)NB * NT * NH + bq * NH + jh0 + joB] = make_float2(hn2[0], hn2[1]);
      *(float2*)&out[(size_t)NB * NT * NH + NB * NH + bq * NH + jh0 + joB] = make_float2(cn2[0], cn2[1]);
    }
  }
}

// ---------------------------------------------------------------------------
extern "C" void kernel_launch(void* const* d_in, const int* in_sizes, int n_in,
                              void* d_out, int out_size, void* d_ws, size_t ws_size,
                              hipStream_t stream) {
  (void)in_sizes; (void)n_in; (void)out_size;
  const float* x    = (const float*)d_in[0];
  const float* Wm   = (const float*)d_in[1];
  const float* Wih  = (const float*)d_in[2];
  const float* Wix  = (const float*)d_in[3];
  const float* bi   = (const float*)d_in[4];
  const float* Wgh  = (const float*)d_in[5];
  const float* Wgx  = (const float*)d_in[6];
  const float* bg   = (const float*)d_in[7];
  const float* Wfh  = (const float*)d_in[8];
  const float* Wfx  = (const float*)d_in[9];
  const float* bfp  = (const float*)d_in[10];
  const float* Woh  = (const float*)d_in[11];
  const float* Wox  = (const float*)d_in[12];
  const float* bo   = (const float*)d_in[13];
  const float* lnig = (const float*)d_in[14];
  const float* lnib = (const float*)d_in[15];
  const float* lngg = (const float*)d_in[16];
  const float* lngb = (const float*)d_in[17];
  const float* lnfg = (const float*)d_in[18];
  const float* lnfb = (const float*)d_in[19];
  const float* lnog = (const float*)d_in[20];
  const float* lnob = (const float*)d_in[21];
  const float* lncg = (const float*)d_in[22];
  const float* lncb = (const float*)d_in[23];
  const float* pzxw = (const float*)d_in[24];
  const float* pzxb = (const float*)d_in[25];
  const float* pzhw = (const float*)d_in[26];
  const float* pzhb = (const float*)d_in[27];
  const float* pzbw = (const float*)d_in[28];
  const float* pzbb = (const float*)d_in[29];
  const float* pdx  = (const float*)d_in[30];
  const float* pdh  = (const float*)d_in[31];
  const float* pbw  = (const float*)d_in[32];
  const float* pbb  = (const float*)d_in[33];
  float* out = (float*)d_out;

  char* ws = (char*)d_ws;
  size_t off = 0;
  auto alloc = [&](size_t bytes) {
    char* p = ws + off; off += (bytes + 255) & ~(size_t)255; return p;
  };
  unsigned short* preall = (unsigned short*)alloc((size_t)16384 * NC4 * 2);
  unsigned short* wcat   = (unsigned short*)alloc((size_t)NC4 * 512 * 2);
  unsigned short* wmht   = (unsigned short*)alloc((size_t)4096 * 1024 * 2);
  unsigned short* whht   = (unsigned short*)alloc((size_t)4 * 128 * 128 * 2);
  float* pzt             = (float*)alloc((size_t)3 * 16 * 128 * 4);
  float* zbuf            = (float*)alloc((size_t)NT * NB * 48 * 4);
  unsigned int* hbuf32   = (unsigned int*)alloc((size_t)2 * NB * NH * 2);
  int* flags             = (int*)alloc((size_t)96 * 4);
  if (off > ws_size) return;  // ws too small: leave output untouched (diagnosable)

  k_prep<<<256, 256, 0, stream>>>(Wih, Wgh, Wfh, Woh, pzxw, pzhw, pzbw, whht, pzt, hbuf32, flags);
  k_twcat<<<2304, 256, 0, stream>>>(Wm, Wix, Wgx, Wfx, Wox, wcat);
  k_twmh<<<4096, 256, 0, stream>>>(Wm, wmht);
  k_gemm<<<4608, 256, 0, stream>>>(x, wcat, preall);
  k_rec<<<96, 256, 0, stream>>>(preall, wmht, whht, pzt, zbuf,
      pdx, pdh, pbw, pbb, bi, bg, bfp, bo,
      lnig, lnib, lngg, lngb, lnfg, lnfb, lnog, lnob, lncg, lncb,
      pzxb, pzhb, pzbb, hbuf32, out, flags);
}

// Round 13
// 3213.501 us; speedup vs baseline: 1.5394x; 1.0347x over previous
//
#include <hip/hip_runtime.h>
#include <cstdint>
#include <cstddef>

#define NB 32       // batch
#define NT 512      // time steps
#define ND 512      // input dim D
#define NH 1024     // hidden H
#define NC4 4608    // 4H + 4*HH (fused GEMM N)

typedef short sh8 __attribute__((ext_vector_type(8)));   // 8 bf16 (raw bits)
typedef float f4  __attribute__((ext_vector_type(4)));
typedef unsigned int u4 __attribute__((ext_vector_type(4)));

__device__ __forceinline__ unsigned short f2bf(float x) {
  union { float f; unsigned u; } v; v.f = x;
  unsigned r = v.u + 0x7FFFu + ((v.u >> 16) & 1u);   // RNE
  return (unsigned short)(r >> 16);
}
__device__ __forceinline__ float bf2f(unsigned short b) {
  union { unsigned u; float f; } v; v.u = ((unsigned)b) << 16; return v.f;
}
__device__ __forceinline__ float blo(unsigned w) { union { unsigned u; float f; } v; v.u = w << 16; return v.f; }
__device__ __forceinline__ float bhi(unsigned w) { union { unsigned u; float f; } v; v.u = w & 0xFFFF0000u; return v.f; }

// MALL-coherent 16B load: bypasses L1/L2 (sc0 sc1).
#define LD16(dst, base, OFFSTR)                                         \
  asm volatile("global_load_dwordx4 %0, %1, off offset:" OFFSTR " sc0 sc1" \
               : "=v"(dst) : "v"(base))

// ---------------------------------------------------------------------------
// prep: hyper gate weights -> bf16 transposed; pz weights -> fp32 transposed;
//       zero h buf0; zero 288 packed flags (256 h-wave flags + 32 z flags)
// ---------------------------------------------------------------------------
__global__ __launch_bounds__(256) void k_prep(
    const float* __restrict__ wih, const float* __restrict__ wgh,
    const float* __restrict__ wfh, const float* __restrict__ woh,
    const float* __restrict__ pzx, const float* __restrict__ pzh,
    const float* __restrict__ pzb,
    unsigned short* __restrict__ whht, float* __restrict__ pzt,
    unsigned int* __restrict__ hbuf32, int* __restrict__ flags)
{
  int idx = blockIdx.x * 256 + threadIdx.x;
  if (idx < 65536) {  // 4*128*128
    int g = idx >> 14, r = idx & 16383, j = r >> 7, k = r & 127;
    const float* w = (g == 0) ? wih : (g == 1) ? wgh : (g == 2) ? wfh : woh;
    whht[idx] = f2bf(w[k * 128 + j]);
  }
  if (idx < 6144) {   // 3*16*128
    int r = idx & 2047, c = r >> 7, k = r & 127;
    int kind = idx >> 11;
    const float* p = (kind == 0) ? pzx : (kind == 1) ? pzh : pzb;
    pzt[idx] = p[k * 16 + c];
    (void)c; (void)k;
  }
  if (idx < 16384)   // zero buf0 (32*1024 bf16) via MALL so bypass-reads see it
    __hip_atomic_store(hbuf32 + idx, 0u, __ATOMIC_RELAXED, __HIP_MEMORY_SCOPE_AGENT);
  if (idx < 288)     // packed flags: [0..255] h (4/block), [256..287] z
    __hip_atomic_store(flags + idx, 0, __ATOMIC_RELAXED, __HIP_MEMORY_SCOPE_AGENT);
}

// ---------------------------------------------------------------------------
// transpose Wcat -> bf16 [n=4608][k=512]: n<4096 from Wm[:512], else Wi/g/f/o_x
// ---------------------------------------------------------------------------
__global__ __launch_bounds__(256) void k_twcat(
    const float* __restrict__ wm, const float* __restrict__ wix,
    const float* __restrict__ wgx, const float* __restrict__ wfx,
    const float* __restrict__ wox, unsigned short* __restrict__ dst)
{
  __shared__ float tile[32][33];
  int bx = blockIdx.x % 144, by = blockIdx.x / 144;
  int n0 = bx * 32, k0 = by * 32;
  int tx = threadIdx.x & 31, ty = threadIdx.x >> 5;
  #pragma unroll
  for (int i = 0; i < 4; i++) {
    int k = k0 + ty + i * 8, n = n0 + tx;
    float v;
    if (n < 4096) v = wm[(size_t)k * 4096 + n];
    else {
      int nn = n - 4096, g = nn >> 7, j = nn & 127;
      const float* w = (g == 0) ? wix : (g == 1) ? wgx : (g == 2) ? wfx : wox;
      v = w[k * 128 + j];
    }
    tile[ty + i * 8][tx] = v;
  }
  __syncthreads();
  #pragma unroll
  for (int i = 0; i < 4; i++)
    dst[(size_t)(n0 + ty + i * 8) * 512 + k0 + tx] = f2bf(tile[tx][ty + i * 8]);
}

// transpose Wm[512:] -> bf16 [n=4096][k=1024]
__global__ __launch_bounds__(256) void k_twmh(
    const float* __restrict__ wm, unsigned short* __restrict__ dst)
{
  __shared__ float tile[32][33];
  int bx = blockIdx.x % 128, by = blockIdx.x / 128;
  int n0 = bx * 32, k0 = by * 32;
  int tx = threadIdx.x & 31, ty = threadIdx.x >> 5;
  #pragma unroll
  for (int i = 0; i < 4; i++)
    tile[ty + i * 8][tx] = wm[(size_t)(512 + k0 + ty + i * 8) * 4096 + n0 + tx];
  __syncthreads();
  #pragma unroll
  for (int i = 0; i < 4; i++)
    dst[(size_t)(n0 + ty + i * 8) * 1024 + k0 + tx] = f2bf(tile[tx][ty + i * 8]);
}

// ---------------------------------------------------------------------------
// Precompute GEMM: M=16384 K=512 N=4608, bf16 MFMA, 128x128 tile, 4 waves.
// n<4096 stored block-major: n' = (jh>>4)*64 + g*16 + (jh&15)
// ---------------------------------------------------------------------------
__global__ __launch_bounds__(256) void k_gemm(
    const float* __restrict__ x, const unsigned short* __restrict__ wt,
    unsigned short* __restrict__ preall)
{
  __shared__ unsigned short la[4096];
  __shared__ unsigned short lb[4096];
  int bid = blockIdx.x;
  int mb = bid % 128, nb = bid / 128;
  int m0 = mb * 128, n0 = nb * 128;
  int tid = threadIdx.x;
  int lane = tid & 63, wid = tid >> 6;
  int wr = (wid >> 1) * 64, wc = (wid & 1) * 64;
  f4 acc[4][4] = {};
  for (int kt = 0; kt < 16; kt++) {
    int k0 = kt * 32;
    __syncthreads();
    {
      int r = tid >> 1, kh = (tid & 1) * 16;
      const float4* srcA = (const float4*)(x + (size_t)(m0 + r) * 512 + k0 + kh);
      unsigned pk[8];
      #pragma unroll
      for (int q = 0; q < 4; q++) {
        float4 f = srcA[q];
        pk[q * 2]     = (unsigned)f2bf(f.x) | ((unsigned)f2bf(f.y) << 16);
        pk[q * 2 + 1] = (unsigned)f2bf(f.z) | ((unsigned)f2bf(f.w) << 16);
      }
      int base = r * 64 + kh * 2;
      u4 v0 = {pk[0], pk[1], pk[2], pk[3]}, v1 = {pk[4], pk[5], pk[6], pk[7]};
      *(u4*)((char*)la + ((base)      ^ ((r & 7) << 4))) = v0;
      *(u4*)((char*)la + ((base + 16) ^ ((r & 7) << 4))) = v1;
    }
    {
      int r = tid >> 1, kh = (tid & 1) * 16;
      const u4* srcB = (const u4*)(wt + (size_t)(n0 + r) * 512 + k0 + kh);
      u4 v0 = srcB[0], v1 = srcB[1];
      int base = r * 64 + kh * 2;
      *(u4*)((char*)lb + ((base)      ^ ((r & 7) << 4))) = v0;
      *(u4*)((char*)lb + ((base + 16) ^ ((r & 7) << 4))) = v1;
    }
    __syncthreads();
    int fo = (lane >> 4) * 16;
    sh8 af[4], bfr[4];
    #pragma unroll
    for (int mt = 0; mt < 4; mt++) {
      int r = wr + mt * 16 + (lane & 15);
      af[mt] = *(sh8*)((char*)la + ((r * 64 + fo) ^ ((r & 7) << 4)));
    }
    #pragma unroll
    for (int nt = 0; nt < 4; nt++) {
      int r = wc + nt * 16 + (lane & 15);
      bfr[nt] = *(sh8*)((char*)lb + ((r * 64 + fo) ^ ((r & 7) << 4)));
    }
    #pragma unroll
    for (int mt = 0; mt < 4; mt++)
      #pragma unroll
      for (int nt = 0; nt < 4; nt++)
        acc[mt][nt] = __builtin_amdgcn_mfma_f32_16x16x32_bf16(af[mt], bfr[nt], acc[mt][nt], 0, 0, 0);
  }
  #pragma unroll
  for (int mt = 0; mt < 4; mt++)
    #pragma unroll
    for (int nt = 0; nt < 4; nt++) {
      f4 a = acc[mt][nt];
      #pragma unroll
      for (int rr = 0; rr < 4; rr++) {
        int m = m0 + wr + mt * 16 + (lane >> 4) * 4 + rr;
        int n = n0 + wc + nt * 16 + (lane & 15);
        int b = m >> 9, t = m & 511;
        int nn;
        if (n < 4096) { int g = n >> 10, jh = n & 1023; nn = (jh >> 4) * 64 + g * 16 + (jh & 15); }
        else nn = n;
        preall[(size_t)(t * 32 + b) * NC4 + nn] = f2bf(a[rr]);
      }
    }
}

// ---------------------------------------------------------------------------
// Fused recurrence: 96 persistent blocks x 256 threads.
// Per-WAVE flags (no publish barrier): flags[4b+w]=t+1 stored right after each
// wave's own vmcnt(0) h-store drain. 2 barriers/step. Staggered vmcnt MFMA.
//   blocks 0..63 : main LSTM, 16 h-cols each, duplication-free h loads.
//   blocks 64..95: hyper LSTM, 1 batch row each; zflag after wave-0 drain.
// ---------------------------------------------------------------------------
__global__ __launch_bounds__(256, 1) void k_rec(
    const unsigned short* __restrict__ preall,
    const unsigned short* __restrict__ wmht,
    const unsigned short* __restrict__ whht,
    const float* __restrict__ pzt,
    float* __restrict__ zbuf,             // [512][32][48] fp32
    const float* __restrict__ pdx, const float* __restrict__ pdh,
    const float* __restrict__ pbw, const float* __restrict__ pbb,
    const float* __restrict__ bi, const float* __restrict__ bg,
    const float* __restrict__ bff, const float* __restrict__ bo,
    const float* __restrict__ lnig, const float* __restrict__ lnib,
    const float* __restrict__ lngg, const float* __restrict__ lngb,
    const float* __restrict__ lnfg, const float* __restrict__ lnfb,
    const float* __restrict__ lnog, const float* __restrict__ lnob,
    const float* __restrict__ lncg, const float* __restrict__ lncb,
    const float* __restrict__ pzxb, const float* __restrict__ pzhb,
    const float* __restrict__ pzbb,
    unsigned int* __restrict__ hbuf32,    // [2][32][512] u32 (bf16 pairs) ping-pong
    float* __restrict__ out,
    int* __restrict__ flags)              // [288]: [0..255] h per-wave, [256..287] z
{
  __shared__ __align__(16) unsigned short wlds[64 * 1024];   // 128KB / hyper scratch
  __shared__ float red[2][32][68];
  __shared__ __align__(16) float zl[32 * 48];
  __shared__ float clds[512];
  __shared__ __align__(16) unsigned wxl[32][32];
  __shared__ float pdl[3][4][16];
  __shared__ float pbbl[16];

  const int tid = threadIdx.x;
  const int lane = tid & 63, wid = tid >> 6;

  if (blockIdx.x >= 64) {
    // =============== HYPER ROLE (b = blockIdx.x - 64) =====================
    float* const hyp  = (float*)wlds;
    float* const pzl  = hyp;          // 48*132 floats
    float* const hhs  = hyp + 6400;   // 128
    float* const chs  = hyp + 6528;   // 128
    float* const actl = hyp + 6656;   // 4*128
    float* const rwav = hyp + 7168;   // 16
    float* const redc = hyp + 7184;   // 4

    const int b = blockIdx.x - 64;
    const int j = tid & 127, gp = tid >> 7;
    const int ga = gp, gb = gp + 2;

    u4 wa[16], wb[16];
    {
      const u4* s = (const u4*)(whht + (size_t)(ga * 128 + j) * 128);
      #pragma unroll
      for (int i = 0; i < 16; i++) wa[i] = s[i];
      const u4* s2 = (const u4*)(whht + (size_t)(gb * 128 + j) * 128);
      #pragma unroll
      for (int i = 0; i < 16; i++) wb[i] = s2[i];
    }
    for (int i = tid; i < 6144; i += 256)
      pzl[(i >> 7) * 132 + (i & 127)] = pzt[i];

    const float* bias_p[4] = {bi, bg, bff, bo};
    const float* lng_p[4]  = {lnig, lngg, lnfg, lnog};
    const float* lnb_p[4]  = {lnib, lngb, lnfb, lnob};
    float bias_a = bias_p[ga][j], bias_b = bias_p[gb][j];
    float lgam_a = lng_p[ga][j],  lbet_a = lnb_p[ga][j];
    float lgam_b = lng_p[gb][j],  lbet_b = lnb_p[gb][j];
    float lcg = 0.f, lcb = 0.f;
    if (tid < 128) { lcg = lncg[j]; lcb = lncb[j]; hhs[j] = 0.f; chs[j] = 0.f; }
    float zbias = 0.f;
    if (tid < 48) {
      int kind = tid >> 4, c = tid & 15;
      zbias = ((kind == 0) ? pzxb : (kind == 1) ? pzhb : pzbb)[c];
    }
    __syncthreads();

    const f4* h4 = (const f4*)hhs;
    for (int t = 0; t < NT; t++) {
      float xa = bf2f(preall[(size_t)(t * 32 + b) * NC4 + 4096 + ga * 128 + j]);
      float xb = bf2f(preall[(size_t)(t * 32 + b) * NC4 + 4096 + gb * 128 + j]);
      float sa = bias_a, sb = bias_b;
      #pragma unroll
      for (int i = 0; i < 16; i++) {
        f4 h0 = h4[2 * i], h1 = h4[2 * i + 1];
        u4 w = wa[i];
        sa += blo(w.x) * h0[0] + bhi(w.x) * h0[1] + blo(w.y) * h0[2] + bhi(w.y) * h0[3]
            + blo(w.z) * h1[0] + bhi(w.z) * h1[1] + blo(w.w) * h1[2] + bhi(w.w) * h1[3];
        w = wb[i];
        sb += blo(w.x) * h0[0] + bhi(w.x) * h0[1] + blo(w.y) * h0[2] + bhi(w.y) * h0[3]
            + blo(w.z) * h1[0] + bhi(w.z) * h1[1] + blo(w.w) * h1[2] + bhi(w.w) * h1[3];
      }
      sa += xa; sb += xb;
      float a1 = sa, a2 = sa * sa, b1 = sb, b2 = sb * sb;
      #pragma unroll
      for (int m = 1; m < 64; m <<= 1) {
        a1 += __shfl_xor(a1, m); a2 += __shfl_xor(a2, m);
        b1 += __shfl_xor(b1, m); b2 += __shfl_xor(b2, m);
      }
      if ((tid & 63) == 0) {
        int w = tid >> 6;
        rwav[w * 4] = a1; rwav[w * 4 + 1] = a2; rwav[w * 4 + 2] = b1; rwav[w * 4 + 3] = b2;
      }
      __syncthreads();
      int w0 = gp * 2, w1 = gp * 2 + 1;
      float sum_a = rwav[w0 * 4] + rwav[w1 * 4],         sq_a = rwav[w0 * 4 + 1] + rwav[w1 * 4 + 1];
      float sum_b = rwav[w0 * 4 + 2] + rwav[w1 * 4 + 2], sq_b = rwav[w0 * 4 + 3] + rwav[w1 * 4 + 3];
      float mean_a = sum_a * 0.0078125f, var_a = sq_a * 0.0078125f - mean_a * mean_a;
      float mean_b = sum_b * 0.0078125f, var_b = sq_b * 0.0078125f - mean_b * mean_b;
      float xn_a = (sa - mean_a) * rsqrtf(var_a + 1e-5f) * lgam_a + lbet_a;
      float xn_b = (sb - mean_b) * rsqrtf(var_b + 1e-5f) * lgam_b + lbet_b;
      float act_a = (ga == 1) ? tanhf(xn_a) : 1.f / (1.f + __expf(-xn_a));
      float act_b = 1.f / (1.f + __expf(-xn_b));
      actl[ga * 128 + j] = act_a;
      actl[gb * 128 + j] = act_b;
      __syncthreads();
      if (tid < 128) {
        float cn = actl[2 * 128 + j] * chs[j] + actl[j] * actl[128 + j];
        chs[j] = cn;
        float c1 = cn, c2 = cn * cn;
        #pragma unroll
        for (int m = 1; m < 64; m <<= 1) { c1 += __shfl_xor(c1, m); c2 += __shfl_xor(c2, m); }
        if ((tid & 63) == 0) { int w = tid >> 6; redc[w * 2] = c1; redc[w * 2 + 1] = c2; }
      }
      __syncthreads();
      if (tid < 128) {
        float sum2 = redc[0] + redc[2], sq2 = redc[1] + redc[3];
        float mean2 = sum2 * 0.0078125f, var2 = sq2 * 0.0078125f - mean2 * mean2;
        hhs[j] = actl[3 * 128 + j] * tanhf((chs[j] - mean2) * rsqrtf(var2 + 1e-5f) * lcg + lcb);
      }
      __syncthreads();
      if (tid < 48) {   // z = hh_new @ pz*_w + pz*_b -> publish via MALL store
        const f4* pr = (const f4*)(pzl + tid * 132);
        float zv = zbias;
        #pragma unroll 8
        for (int q = 0; q < 32; q++) {
          f4 p = pr[q], hv = h4[q];
          zv += p[0] * hv[0] + p[1] * hv[1] + p[2] * hv[2] + p[3] * hv[3];
        }
        union { float f; unsigned u; } cv; cv.f = zv;
        __hip_atomic_store((unsigned*)zbuf + (size_t)(t * 32 + b) * 48 + tid, cv.u,
                           __ATOMIC_RELAXED, __HIP_MEMORY_SCOPE_AGENT);
      }
      if (wid == 0) {   // z stores are wave-0-only: drain own wave, flag now
        asm volatile("s_waitcnt vmcnt(0)" ::: "memory");
        if (tid == 0)
          __hip_atomic_store(flags + 256 + b, t + 1, __ATOMIC_RELAXED,
                             __HIP_MEMORY_SCOPE_AGENT);
      }
      __syncthreads();   // protects hhs/actl reuse
    }
    return;
  }

  // ================= MAIN ROLE (blockIdx.x < 64) ==========================
  const int jh0 = blockIdx.x * 16;
  const int jw0 = blockIdx.x * 8;              // u32 col offset in hbuf32

  {   // stage weight slice once: n = g*16+jo -> wmht row g*NH + jh0 + jo
    int n = tid >> 2, kc = (tid & 3) * 256;
    int g = n >> 4, jo = n & 15;
    const unsigned short* src = wmht + (size_t)(g * NH + jh0 + jo) * NH + kc;
    #pragma unroll
    for (int i = 0; i < 32; i++) {
      sh8 v = *(const sh8*)(src + i * 8);
      int byte = n * 2048 + (kc + i * 8) * 2;
      *(sh8*)((char*)wlds + (byte ^ ((n & 7) << 4))) = v;
    }
  }
  clds[tid] = 0.f; clds[tid + 256] = 0.f;
  if (tid < 192) {
    int kind = tid >> 6, e = (tid >> 4) & 3, jo = tid & 15;
    const float* p = (kind == 0) ? pdx : (kind == 1) ? pdh : pbw;
    pdl[kind][e][jo] = p[e * NH + jh0 + jo];
  }
  if (tid < 16) pbbl[tid] = pbb[jh0 + tid];
  __syncthreads();

  const int bq = tid >> 3;       // combine row b: 0..31
  const int joB = (tid & 7) * 2; // combine adjacent col pair
  const int kh = wid >> 1;       // K-half
  const int rh = wid & 1;        // row-half
  const int col = lane & 15;
  const int grp = lane >> 4;     // 0..3
  const int row = rh * 16 + col; // the single b-row this lane loads

  // poll: each lane covers 4 h-wave-flags; lanes 0-7 also cover 32 z flags
  const int* fbh = flags + lane * 4;
  const int* fbz = flags + 256 + ((lane < 8) ? lane : 0) * 4;

#define WAITN(N) asm volatile("s_waitcnt vmcnt(" #N ")" ::: "memory"); __builtin_amdgcn_sched_barrier(0)
#define PROCK(ks)                                                              \
  {                                                                            \
    int kb = kh * 512 + (ks) * 32 + grp * 8;                                   \
    union { u4 u; sh8 s; } A; A.u = ar[ks];                                    \
    int n0 = col, n1 = 16 + col, n2 = 32 + col, n3 = 48 + col;                 \
    sh8 b0 = *(sh8*)((char*)wlds + ((n0 * 2048 + kb * 2) ^ ((n0 & 7) << 4)));  \
    sh8 b1 = *(sh8*)((char*)wlds + ((n1 * 2048 + kb * 2) ^ ((n1 & 7) << 4)));  \
    sh8 b2 = *(sh8*)((char*)wlds + ((n2 * 2048 + kb * 2) ^ ((n2 & 7) << 4)));  \
    sh8 b3 = *(sh8*)((char*)wlds + ((n3 * 2048 + kb * 2) ^ ((n3 & 7) << 4)));  \
    acc0 = __builtin_amdgcn_mfma_f32_16x16x32_bf16(A.s, b0, acc0, 0, 0, 0);    \
    acc1 = __builtin_amdgcn_mfma_f32_16x16x32_bf16(A.s, b1, acc1, 0, 0, 0);    \
    acc2 = __builtin_amdgcn_mfma_f32_16x16x32_bf16(A.s, b2, acc2, 0, 0, 0);    \
    acc3 = __builtin_amdgcn_mfma_f32_16x16x32_bf16(A.s, b3, acc3, 0, 0, 0);    \
  }

  for (int t = 0; t < NT; t++) {
    // ---- stage wx slab (cached, block-major preall) -----------------------
    {
      const u4* s = (const u4*)(preall + (size_t)(t * 32 + bq) * NC4
                                + (size_t)blockIdx.x * 64 + (tid & 7) * 8);
      *(u4*)&wxl[bq][(tid & 7) * 4] = *s;
    }
    // ---- wait for h(t) (256 wave-flags) and z(t): wave0 poll --------------
    if (wid == 0) {
      for (;;) {
        u4 f, g;
        LD16(f, fbh, "0");
        if (lane < 8) LD16(g, fbz, "0");
        asm volatile("s_waitcnt vmcnt(0)" ::: "memory");
        int ok = ((int)f.x >= t) & ((int)f.y >= t) & ((int)f.z >= t) & ((int)f.w >= t);
        if (lane < 8)
          ok &= ((int)g.x > t) & ((int)g.y > t) & ((int)g.z > t) & ((int)g.w > t);
        if (__all(ok)) break;
      }
    }
    __syncthreads();
    asm volatile("" ::: "memory");
    if (tid < 192) {   // stage z(t) into LDS (data guaranteed by zflag)
      const f4* zs = (const f4*)(zbuf + (size_t)t * NB * 48) + tid * 2;
      f4 a = zs[0], bz = zs[1];
      f4* zd = (f4*)zl + tid * 2;
      zd[0] = a; zd[1] = bz;
    }
    const unsigned int* hc32 = hbuf32 + (t & 1) * (NB * NH / 2);
    // ---- W_h: wave = (kh, rh): 16 rows x K-half, staggered vmcnt ----------
    {
      const unsigned int* bp = hc32 + row * 512 + kh * 256 + grp * 4;
      u4 ar[16];
      LD16(ar[0],  bp, "0");    LD16(ar[1],  bp, "64");
      LD16(ar[2],  bp, "128");  LD16(ar[3],  bp, "192");
      LD16(ar[4],  bp, "256");  LD16(ar[5],  bp, "320");
      LD16(ar[6],  bp, "384");  LD16(ar[7],  bp, "448");
      LD16(ar[8],  bp, "512");  LD16(ar[9],  bp, "576");
      LD16(ar[10], bp, "640");  LD16(ar[11], bp, "704");
      LD16(ar[12], bp, "768");  LD16(ar[13], bp, "832");
      LD16(ar[14], bp, "896");  LD16(ar[15], bp, "960");
      f4 acc0 = {0,0,0,0}, acc1 = {0,0,0,0}, acc2 = {0,0,0,0}, acc3 = {0,0,0,0};
      WAITN(8);
      PROCK(0); PROCK(1); PROCK(2); PROCK(3);
      PROCK(4); PROCK(5); PROCK(6); PROCK(7);
      WAITN(4);
      PROCK(8); PROCK(9); PROCK(10); PROCK(11);
      WAITN(0);
      PROCK(12); PROCK(13); PROCK(14); PROCK(15);
      int r0 = rh * 16 + grp * 4;
      #pragma unroll
      for (int rr = 0; rr < 4; rr++) {
        red[kh][r0 + rr][col]      = acc0[rr];
        red[kh][r0 + rr][16 + col] = acc1[rr];
        red[kh][r0 + rr][32 + col] = acc2[rr];
        red[kh][r0 + rr][48 + col] = acc3[rr];
      }
    }
    __syncthreads();
    // ---- combine: thread (bq, joB) handles adjacent jo = joB, joB+1 ------
    float hn2[2], cn2[2];
    {
      const float* zb_ = zl + bq * 48;
      const unsigned short* wxp = (const unsigned short*)&wxl[bq][0];
      #pragma unroll
      for (int half = 0; half < 2; half++) {
        int jo = joB + half;
        float gv[4];
        #pragma unroll
        for (int g = 0; g < 4; g++) {
          float wh = red[0][bq][g * 16 + jo] + red[1][bq][g * 16 + jo];
          float dxv = 0.f, dhv = 0.f, bdv = pbbl[jo];
          #pragma unroll
          for (int e = 0; e < 4; e++) {
            dxv += zb_[g * 4 + e]      * pdl[0][e][jo];
            dhv += zb_[16 + g * 4 + e] * pdl[1][e][jo];
            bdv += zb_[32 + g * 4 + e] * pdl[2][e][jo];
          }
          float wxv = bf2f(wxp[g * 16 + jo]);
          gv[g] = wxv * dxv + wh * dhv + bdv;
        }
        float iv = 1.f / (1.f + __expf(-gv[0]));
        float fv = 1.f / (1.f + __expf(-gv[1]));
        float ov = 1.f / (1.f + __expf(-gv[2]));
        float gg = tanhf(gv[3]);
        int ci = bq * 16 + jo;
        float cn = fv * clds[ci] + iv * gg;
        clds[ci] = cn;
        hn2[half] = ov * tanhf(cn);
        cn2[half] = cn;
      }
      // publish h(t+1): only store before the per-wave drain
      unsigned val = (unsigned)f2bf(hn2[0]) | ((unsigned)f2bf(hn2[1]) << 16);
      __hip_atomic_store(hbuf32 + ((t + 1) & 1) * (NB * NH / 2) + bq * 512 + jw0 + (joB >> 1),
                         val, __ATOMIC_RELAXED, __HIP_MEMORY_SCOPE_AGENT);
    }
    // ---- per-wave drain + per-wave flag (NO barrier); out[] after --------
    asm volatile("s_waitcnt vmcnt(0)" ::: "memory");
    if (lane == 0)
      __hip_atomic_store(flags + blockIdx.x * 4 + wid, t + 1, __ATOMIC_RELAXED,
                         __HIP_MEMORY_SCOPE_AGENT);
    *(float2*)&out[(size_t)(bq * NT + t) * NH + jh0 + joB] = make_float2(hn2[0], hn2[1]);
    if (t == NT - 1) {
      *(float2*)&out[(size_t)NB * NT * NH + bq * NH + jh0 + joB] = make_float2(hn2[0], hn2[1]);
      *(float2*)&out[(size_t)NB * NT * NH + NB * NH + bq * NH + jh0 + joB] = make_float2(cn2[0], cn2[1]);
    }
    // NOTE: no third barrier. Safety: each wave's red/zl/wxl reads precede its
    // flag store; next-step writes to red/zl happen only after the post-poll
    // barrier, which requires ALL local wave flags >= t+1.
  }
#undef WAITN
#undef PROCK
}

// ---------------------------------------------------------------------------
extern "C" void kernel_launch(void* const* d_in, const int* in_sizes, int n_in,
                              void* d_out, int out_size, void* d_ws, size_t ws_size,
                              hipStream_t stream) {
  (void)in_sizes; (void)n_in; (void)out_size;
  const float* x    = (const float*)d_in[0];
  const float* Wm   = (const float*)d_in[1];
  const float* Wih  = (const float*)d_in[2];
  const float* Wix  = (const float*)d_in[3];
  const float* bi   = (const float*)d_in[4];
  const float* Wgh  = (const float*)d_in[5];
  const float* Wgx  = (const float*)d_in[6];
  const float* bg   = (const float*)d_in[7];
  const float* Wfh  = (const float*)d_in[8];
  const float* Wfx  = (const float*)d_in[9];
  const float* bfp  = (const float*)d_in[10];
  const float* Woh  = (const float*)d_in[11];
  const float* Wox  = (const float*)d_in[12];
  const float* bo   = (const float*)d_in[13];
  const float* lnig = (const float*)d_in[14];
  const float* lnib = (const float*)d_in[15];
  const float* lngg = (const float*)d_in[16];
  const float* lngb = (const float*)d_in[17];
  const float* lnfg = (const float*)d_in[18];
  const float* lnfb = (const float*)d_in[19];
  const float* lnog = (const float*)d_in[20];
  const float* lnob = (const float*)d_in[21];
  const float* lncg = (const float*)d_in[22];
  const float* lncb = (const float*)d_in[23];
  const float* pzxw = (const float*)d_in[24];
  const float* pzxb = (const float*)d_in[25];
  const float* pzhw = (const float*)d_in[26];
  const float* pzhb = (const float*)d_in[27];
  const float* pzbw = (const float*)d_in[28];
  const float* pzbb = (const float*)d_in[29];
  const float* pdx  = (const float*)d_in[30];
  const float* pdh  = (const float*)d_in[31];
  const float* pbw  = (const float*)d_in[32];
  const float* pbb  = (const float*)d_in[33];
  float* out = (float*)d_out;

  char* ws = (char*)d_ws;
  size_t off = 0;
  auto alloc = [&](size_t bytes) {
    char* p = ws + off; off += (bytes + 255) & ~(size_t)255; return p;
  };
  unsigned short* preall = (unsigned short*)alloc((size_t)16384 * NC4 * 2);
  unsigned short* wcat   = (unsigned short*)alloc((size_t)NC4 * 512 * 2);
  unsigned short* wmht   = (unsigned short*)alloc((size_t)4096 * 1024 * 2);
  unsigned short* whht   = (unsigned short*)alloc((size_t)4 * 128 * 128 * 2);
  float* pzt             = (float*)alloc((size_t)3 * 16 * 128 * 4);
  float* zbuf            = (float*)alloc((size_t)NT * NB * 48 * 4);
  unsigned int* hbuf32   = (unsigned int*)alloc((size_t)2 * NB * NH * 2);
  int* flags             = (int*)alloc((size_t)288 * 4);
  if (off > ws_size) return;  // ws too small: leave output untouched (diagnosable)

  k_prep<<<256, 256, 0, stream>>>(Wih, Wgh, Wfh, Woh, pzxw, pzhw, pzbw, whht, pzt, hbuf32, flags);
  k_twcat<<<2304, 256, 0, stream>>>(Wm, Wix, Wgx, Wfx, Wox, wcat);
  k_twmh<<<4096, 256, 0, stream>>>(Wm, wmht);
  k_gemm<<<4608, 256, 0, stream>>>(x, wcat, preall);
  k_rec<<<96, 256, 0, stream>>>(preall, wmht, whht, pzt, zbuf,
      pdx, pdh, pbw, pbb, bi, bg, bfp, bo,
      lnig, lnib, lngg, lngb, lnfg, lnfb, lnog, lnob, lncg, lncb,
      pzxb, pzhb, pzbb, hbuf32, out, flags);
}